// Round 8
// baseline (2708.670 us; speedup 1.0000x reference)
//
#include <hip/hip_runtime.h>
#include <hip/hip_bf16.h>

#define NB  4096
#define NT  128
#define ND  64
#define NV  65
#define NL  3
#define NH  8
#define NDF 256
#define NBT (NB*NT)

// fp32 param offsets inside d_ws (element counts)
#define OFF_TOK   0
#define OFF_POS   4160
#define OFF_LN1G  12352
#define OFF_LN1B  12544
#define OFF_WQ    12736
#define OFF_WK    25024
#define OFF_WV    37312
#define OFF_WO    49600
#define OFF_BO    61888
#define OFF_LN2G  62080
#define OFF_LN2B  62272
#define OFF_W1    62464
#define OFF_B1    111616
#define OFF_W2    112384
#define OFF_B2    161536
#define OFF_LNFG  161728
#define OFF_LNFB  161792
#define OFF_LMW   161856
#define OFF_LMB   166016
#define CVT_TOTAL 166081
#define OFF_LOSS  166144   // fp32 loss accumulator slot
#define OFF_FLAG  166145   // flags: bit0 fp32 floats; bit2 int32 ints; bit3 MFMA-layout-BAD

// packed bf16 weights (hi + lo) appended after flag
#define PKF       166148            // float offset of packed region
#define PK_ELEMS  151552            // bf16 elements (hi); lo mirrors at +PK_ELEMS
#define PKLO      151552
#define NEED_WS   ((size_t)(PKF + PK_ELEMS) * 4)

typedef short s8v  __attribute__((ext_vector_type(8)));
typedef float f4v  __attribute__((ext_vector_type(4)));

struct CvtArgs { const void* p[19]; };

__device__ __forceinline__ unsigned short f2bf(float x) {
    unsigned int u = __float_as_uint(x);
    u = (u + 0x7fffu + ((u >> 16) & 1u)) >> 16;   // RNE
    return (unsigned short)u;
}
__device__ __forceinline__ float bf2f(unsigned short h) {
    return __uint_as_float(((unsigned int)h) << 16);
}
__device__ __forceinline__ f4v mfma16(s8v a, s8v b, f4v c) {
    return __builtin_amdgcn_mfma_f32_16x16x32_bf16(a, b, c, 0, 0, 0);
}

__global__ void diag_fill(float* __restrict__ out, int n, float val) {
    int i = blockIdx.x * 256 + threadIdx.x;
    if (i < n) out[i] = val;
}

__global__ void detect_float(const unsigned short* __restrict__ tok,
                             int* __restrict__ flags) {
    int bad = 0;
    for (int i = threadIdx.x; i < 4096; i += 256) {
        float v = __uint_as_float(((unsigned int)tok[i]) << 16);
        if (!(fabsf(v) < 1000.f)) bad = 1;
    }
    if (bad) atomicOr(flags, 1);
}

__global__ void detect_int(const int* __restrict__ idx32,
                           int* __restrict__ flags) {
    int proven = 0;
    #pragma unroll
    for (int j = 0; j < 8; j++) {
        int slot = 2 * (threadIdx.x * 8 + j) + 1;
        if (idx32[slot] != 0) proven = 1;
    }
    if (proven) atomicOr(flags, 4);
}

// param conversion (bf16 or fp32 -> fp32) into workspace
__global__ void cvt_params(CvtArgs a, float* __restrict__ W,
                           const int* __restrict__ flags) {
    int tid = blockIdx.x * 256 + threadIdx.x;
    if (tid >= CVT_TOTAL) return;
    const int offs[20] = {0,4160,12352,12544,12736,25024,37312,49600,61888,
                          62080,62272,62464,111616,112384,161536,161728,
                          161792,161856,166016,166081};
    int s = 0;
    #pragma unroll
    for (int k = 1; k < 19; k++) s += (tid >= offs[k]);
    int local = tid - offs[s];
    if (*flags & 1) {
        W[tid] = ((const float*)a.p[s])[local];
    } else {
        unsigned int v = ((const unsigned short*)a.p[s])[local];
        W[tid] = __uint_as_float(v << 16);
    }
}

// Pack matmul weights into MFMA b-frag order, hi+lo bf16.
// B-frag: lane l elem e holds B[kt*32 + (l>>4)*8 + e][nt*16 + (l&15)]
__global__ void pack_weights(const float* __restrict__ W,
                             unsigned short* __restrict__ pkw) {
    int p = blockIdx.x * 256 + threadIdx.x;
    if (p >= PK_ELEMS) return;
    int srcoff, K, N, perlay, local, ktbits;
    if (p < 49152) {
        int grp = p / 12288; local = p % 12288;
        srcoff = (grp == 0) ? OFF_WQ : (grp == 1) ? OFF_WK
               : (grp == 2) ? OFF_WV : OFF_WO;
        K = 64; N = 64; perlay = 4096; ktbits = 1;
    } else if (p < 98304) {
        local = p - 49152; srcoff = OFF_W1; K = 64; N = 256;
        perlay = 16384; ktbits = 1;
    } else if (p < 147456) {
        local = p - 98304; srcoff = OFF_W2; K = 256; N = 64;
        perlay = 16384; ktbits = 3;
    } else {
        local = p - 147456; srcoff = OFF_LMW; K = 64; N = 65;   // lm head, cols 0..63
        perlay = 4096; ktbits = 1;
    }
    int lay = local / perlay, rem = local % perlay;
    int t = rem >> 9, le = rem & 511, l = le >> 3, e = le & 7;
    int kt = t & ((1 << ktbits) - 1), nt = t >> ktbits;
    int row = kt * 32 + (l >> 4) * 8 + e;
    int col = nt * 16 + (l & 15);
    float v = W[srcoff + lay * K * N + row * N + col];
    unsigned short hi = f2bf(v);
    pkw[p] = hi;
    pkw[PKLO + p] = f2bf(v - bf2f(hi));
}

// Verify A/B operand layout vs HW-verified C/D layout (asymmetric ints).
__global__ void mfma_probe(int* __restrict__ flags) {
    int l = threadIdx.x;
    s8v av, bv;
    int i = l & 15;
    #pragma unroll
    for (int e = 0; e < 8; e++) {
        int k = (l >> 4) * 8 + e;
        av[e] = (short)f2bf((float)(((i * 5 + k * 3) & 7) - 3));
        bv[e] = (short)f2bf((float)(((k * 7 + i * 11) & 7) - 4));
    }
    f4v c = {0.f, 0.f, 0.f, 0.f};
    c = mfma16(av, bv, c);
    int bad = 0;
    #pragma unroll
    for (int reg = 0; reg < 4; reg++) {
        int row = (l >> 4) * 4 + reg, col = l & 15;
        float exp = 0.f;
        for (int k = 0; k < 32; k++)
            exp += (float)(((row * 5 + k * 3) & 7) - 3) *
                   (float)(((k * 7 + col * 11) & 7) - 4);
        if (c[reg] != exp) bad = 1;
    }
    if (bad) atomicOr(flags, 8);
}

__device__ __forceinline__ void unpack8(uint4 u, float* f) {
    f[0] = __uint_as_float(u.x << 16); f[1] = __uint_as_float(u.x & 0xffff0000u);
    f[2] = __uint_as_float(u.y << 16); f[3] = __uint_as_float(u.y & 0xffff0000u);
    f[4] = __uint_as_float(u.z << 16); f[5] = __uint_as_float(u.z & 0xffff0000u);
    f[6] = __uint_as_float(u.w << 16); f[7] = __uint_as_float(u.w & 0xffff0000u);
}

// LayerNorm over D=64, 8 threads/row, fp32 row-major out (VALU path helper)
__device__ __forceinline__ void ln_rm(const float (*src)[68], float (*dst)[68],
                                      const float* __restrict__ g,
                                      const float* __restrict__ bb, int tid) {
    int r = tid >> 3, q = tid & 7;
    int c0 = q * 8;
    float s = 0.f, s2 = 0.f;
    #pragma unroll
    for (int c = 0; c < 8; c++) { float v = src[r][c0 + c]; s += v; s2 += v * v; }
    s += __shfl_xor(s, 1);  s2 += __shfl_xor(s2, 1);
    s += __shfl_xor(s, 2);  s2 += __shfl_xor(s2, 2);
    s += __shfl_xor(s, 4);  s2 += __shfl_xor(s2, 4);
    float mu   = s  * (1.f / 64.f);
    float var  = s2 * (1.f / 64.f) - mu * mu;
    float rstd = rsqrtf(var + 1e-5f);
    #pragma unroll
    for (int c = 0; c < 8; c++) {
        int cc = c0 + c;
        dst[r][cc] = (src[r][cc] - mu) * rstd * g[cc] + bb[cc];
    }
}

// LayerNorm writing bf16-hi a-frag layout: elem (r,col) at
// (((r>>4)*2 + (col>>5))*64 + ((col>>3)&3)*16 + (r&15))*8 + (col&7)
__device__ __forceinline__ void ln_frag_hi(const float (*src)[68],
        unsigned short* __restrict__ dhi,
        const float* __restrict__ g, const float* __restrict__ bb, int tid) {
    int r = tid >> 3, q = tid & 7, c0 = q * 8;
    float s = 0.f, s2 = 0.f;
    #pragma unroll
    for (int c = 0; c < 8; c++) { float v = src[r][c0 + c]; s += v; s2 += v * v; }
    s += __shfl_xor(s, 1);  s2 += __shfl_xor(s2, 1);
    s += __shfl_xor(s, 2);  s2 += __shfl_xor(s2, 2);
    s += __shfl_xor(s, 4);  s2 += __shfl_xor(s2, 4);
    float mu   = s  * (1.f / 64.f);
    float var  = s2 * (1.f / 64.f) - mu * mu;
    float rstd = rsqrtf(var + 1e-5f);
    unsigned uh[4];
    #pragma unroll
    for (int c2 = 0; c2 < 4; c2++) {
        float y0 = (src[r][c0 + c2*2    ] - mu) * rstd * g[c0 + c2*2    ] + bb[c0 + c2*2    ];
        float y1 = (src[r][c0 + c2*2 + 1] - mu) * rstd * g[c0 + c2*2 + 1] + bb[c0 + c2*2 + 1];
        uh[c2] = (unsigned)f2bf(y0) | ((unsigned)f2bf(y1) << 16);
    }
    int di = (((r >> 4) * 2 + (q >> 2)) * 64 + (q & 3) * 16 + (r & 15)) * 8;
    *(uint4*)(dhi + di) = make_uint4(uh[0], uh[1], uh[2], uh[3]);
}

// 16 FMAs of one activation row segment against cached weights (VALU path)
__device__ __forceinline__ void fma16(const float* xr, const float* wr, float& a) {
    float4 x0 = *(const float4*)(xr);
    float4 x1 = *(const float4*)(xr + 4);
    float4 x2 = *(const float4*)(xr + 8);
    float4 x3 = *(const float4*)(xr + 12);
    a = fmaf(x0.x, wr[0],  a); a = fmaf(x0.y, wr[1],  a);
    a = fmaf(x0.z, wr[2],  a); a = fmaf(x0.w, wr[3],  a);
    a = fmaf(x1.x, wr[4],  a); a = fmaf(x1.y, wr[5],  a);
    a = fmaf(x1.z, wr[6],  a); a = fmaf(x1.w, wr[7],  a);
    a = fmaf(x2.x, wr[8],  a); a = fmaf(x2.y, wr[9],  a);
    a = fmaf(x2.z, wr[10], a); a = fmaf(x2.w, wr[11], a);
    a = fmaf(x3.x, wr[12], a); a = fmaf(x3.y, wr[13], a);
    a = fmaf(x3.z, wr[14], a); a = fmaf(x3.w, wr[15], a);
}

// scalar LN for the self-check path
__device__ void ln_scalar(const float* x, float* o,
                          const float* g, const float* bb) {
    float mu = 0.f;
    for (int i = 0; i < ND; i++) mu += x[i];
    mu *= (1.f / 64.f);
    float var = 0.f;
    for (int i = 0; i < ND; i++) { float d = x[i] - mu; var += d * d; }
    var *= (1.f / 64.f);
    float rstd = rsqrtf(var + 1e-5f);
    for (int i = 0; i < ND; i++) o[i] = (x[i] - mu) * rstd * g[i] + bb[i];
}

// write one attention-output quad (packed bf16 pairs) into xah a-frag layout
__device__ __forceinline__ void store_o(unsigned short* xah, int mt, int head,
                                        int g, int cl, unsigned pk0, unsigned pk1) {
    if (cl < 8) {
        unsigned pk[2] = {pk0, pk1};
        #pragma unroll
        for (int i2 = 0; i2 < 4; i2++) {
            int r = mt * 16 + g * 4 + i2;
            int col = head * 8 + cl;
            unsigned v = pk[i2 >> 1];
            unsigned short hv = (unsigned short)((i2 & 1) ? (v >> 16) : (v & 0xffffu));
            int di = (((r >> 4) * 2 + (col >> 5)) * 64 + ((col >> 3) & 3) * 16
                      + (r & 15)) * 8 + (col & 7);
            xah[di] = hv;
        }
    }
}

// ======================= main MFMA kernel: 512 threads, 2 blocks/CU ===========
// R7 lesson: stalls are in-phase latency, not barrier count. Fix: LDS 75.8KB
// (< 80KB) + 8-wave blocks -> TWO independent blocks co-resident per CU; when
// one block stalls at a barrier/load, the other's waves fill the SIMDs.
// launch_bounds(512,4): 4 waves/EU min = 2 blocks/CU -> 128 VGPR cap.
__global__ __launch_bounds__(512, 4) void gpt_fwd(
    const float* __restrict__ W, const unsigned short* __restrict__ pkw,
    int usepk, const void* __restrict__ idxp, const void* __restrict__ tgtp,
    float* __restrict__ out, float* __restrict__ loss_acc,
    const int* __restrict__ flags)
{
    __shared__ alignas(16) float xs[NT][68];            // residual, 34816B
    __shared__ alignas(16) unsigned short xah[8192];    // A-frag hi, 16384B
    __shared__ alignas(16) unsigned short uni[12288];   // q/k/vb half OR hidden, 24576B
    __shared__ alignas(16) unsigned short zblk[8];      // 16B zeros
    __shared__ float wsum[8];

    unsigned short* q_l = uni;                          // [4][128][8]
    unsigned short* k_l = uni + 4096;                   // [4][128][8]
    unsigned short* vb  = uni + 8192;                   // [4][4kt][4g][8c][8e]
    unsigned short* ha  = uni;                          // FFN hidden chunk [2][8][64][8]

    const int tid  = threadIdx.x;
    const int lane = tid & 63;
    const int w    = tid >> 6;                          // 0..7
    const int cl   = lane & 15;
    const int g    = lane >> 4;
    const int b    = blockIdx.x;
    const int fl   = *flags;
    if (!usepk || (fl & 8)) return;                     // fallback kernel will run
    const bool i64 = !(fl & 4);
    const int*       idx32 = (const int*)idxp;
    const long long* idx64 = (const long long*)idxp;
    const int*       tgt32 = (const int*)tgtp;
    const long long* tgt64 = (const long long*)tgtp;

    if (tid < 8) zblk[tid] = 0;

    // ---- embed: x = tok_emb[idx] + pos_emb ----
    for (int e = tid * 4; e < NT * ND; e += 2048) {
        int r = e >> 6, c = e & 63;
        int n = b * NT + r;
        int tok = i64 ? (int)idx64[n] : idx32[n];
        float4 te = *(const float4*)&W[OFF_TOK + tok * ND + c];
        float4 pe = *(const float4*)&W[OFF_POS + r * ND + c];
        float4 xv;
        xv.x = te.x + pe.x; xv.y = te.y + pe.y;
        xv.z = te.z + pe.z; xv.w = te.w + pe.w;
        *(float4*)&xs[r][c] = xv;
    }
    __syncthreads();

    for (int lay = 0; lay < NL; lay++) {
        ln_frag_hi(xs, xah, W + OFF_LN1G + lay * 64, W + OFF_LN1B + lay * 64, tid);
        ln_frag_hi(xs, xah, W + OFF_LN1G + lay * 64, W + OFF_LN1B + lay * 64, tid + 512);
        __syncthreads();

        // half-0 attn-out stash: per-lane packed bf16 pairs, named registers
        unsigned st0a = 0, st0b = 0, st1a = 0, st1b = 0;
        unsigned st2a = 0, st2b = 0, st3a = 0, st3b = 0;

        #pragma unroll 1
        for (int hf = 0; hf < 2; hf++) {
            // ---- QKV half: 48 tiles, 6/wave ----
            {
                const unsigned short* pbase = pkw + lay * 4096;
                #pragma unroll 1
                for (int i = 0; i < 6; i++) {
                    int ft = w * 6 + i;                 // 0..47
                    int mat = ft >> 4;
                    int mt  = (ft >> 1) & 7;
                    int ntg = hf * 2 + (ft & 1);
                    const unsigned short* pb = pbase + mat * 12288 + ntg * 1024 + lane * 8;
                    f4v acc = {0.f, 0.f, 0.f, 0.f};
                    #pragma unroll
                    for (int kt = 0; kt < 2; kt++) {
                        s8v ah = *(const s8v*)(xah + ((mt * 2 + kt) * 64 + lane) * 8);
                        s8v bh = *(const s8v*)(pb + kt * 512);
                        s8v bl = *(const s8v*)(pb + PKLO + kt * 512);
                        acc = mfma16(ah, bh, acc);
                        acc = mfma16(ah, bl, acc);
                    }
                    int row0 = mt * 16 + g * 4;
                    int fullcol = ntg * 16 + cl;
                    int hl2 = (fullcol >> 3) & 3;
                    int dim = fullcol & 7;
                    if (mat == 0) {
                        #pragma unroll
                        for (int i2 = 0; i2 < 4; i2++)
                            q_l[(hl2 * 128 + row0 + i2) * 8 + dim] =
                                f2bf(acc[i2] * 0.35355339059327373f);
                    } else if (mat == 1) {
                        #pragma unroll
                        for (int i2 = 0; i2 < 4; i2++)
                            k_l[(hl2 * 128 + row0 + i2) * 8 + dim] = f2bf(acc[i2]);
                    } else {
                        #pragma unroll
                        for (int i2 = 0; i2 < 4; i2++) {
                            int key = row0 + i2;
                            vb[((hl2 * 4 + (key >> 5)) * 4 + ((key >> 3) & 3)) * 64
                               + dim * 8 + (key & 7)] = f2bf(acc[i2]);
                        }
                    }
                }
            }
            __syncthreads();

            // ---- attention half: S^T = mfma(K,Q), softmax, reg P-transpose ----
            // tiles t = w + ti*8 (0..31): headl = t&3, mt = t>>2
            {
                #pragma unroll 1
                for (int ti = 0; ti < 4; ti++) {
                    int t = w + ti * 8;
                    int headl = t & 3, mt = t >> 2;
                    const unsigned short* qsrc = (lane < 16)
                        ? q_l + (headl * 128 + mt * 16 + cl) * 8 : zblk;
                    s8v qb = *(const s8v*)qsrc;
                    float m = -1e30f, lsum = 0.f;
                    f4v o = {0.f, 0.f, 0.f, 0.f};
                    const int ktmax = mt >> 1;
                    #pragma unroll 1
                    for (int kt = 0; kt <= ktmax; kt++) {
                        f4v p0, p1;
                        {
                            const unsigned short* ksrc = (lane < 16)
                                ? k_l + (headl * 128 + (kt * 2) * 16 + cl) * 8 : zblk;
                            s8v kb = *(const s8v*)ksrc;
                            f4v s0 = {0.f, 0.f, 0.f, 0.f};
                            s0 = mfma16(kb, qb, s0);
                            if (kt * 2 == mt) {
                                #pragma unroll
                                for (int i2 = 0; i2 < 4; i2++)
                                    s0[i2] = (g * 4 + i2 <= cl) ? s0[i2] : -1e30f;
                            }
                            p0 = s0;
                        }
                        if (kt * 2 + 1 <= mt) {
                            const unsigned short* ksrc = (lane < 16)
                                ? k_l + (headl * 128 + (kt * 2 + 1) * 16 + cl) * 8 : zblk;
                            s8v kb = *(const s8v*)ksrc;
                            f4v s1 = {0.f, 0.f, 0.f, 0.f};
                            s1 = mfma16(kb, qb, s1);
                            if (kt * 2 + 1 == mt) {
                                #pragma unroll
                                for (int i2 = 0; i2 < 4; i2++)
                                    s1[i2] = (g * 4 + i2 <= cl) ? s1[i2] : -1e30f;
                            }
                            p1 = s1;
                        } else {
                            p1 = (f4v){-1e30f, -1e30f, -1e30f, -1e30f};
                        }
                        float bm = fmaxf(fmaxf(fmaxf(p0[0], p0[1]), fmaxf(p0[2], p0[3])),
                                         fmaxf(fmaxf(p1[0], p1[1]), fmaxf(p1[2], p1[3])));
                        bm = fmaxf(bm, __shfl_xor(bm, 16));
                        bm = fmaxf(bm, __shfl_xor(bm, 32));
                        float nm  = fmaxf(m, bm);
                        float fac = __expf(m - nm);
                        float ps = 0.f;
                        #pragma unroll
                        for (int i2 = 0; i2 < 4; i2++) {
                            p0[i2] = __expf(p0[i2] - nm); ps += p0[i2];
                            p1[i2] = __expf(p1[i2] - nm); ps += p1[i2];
                        }
                        ps += __shfl_xor(ps, 16);
                        ps += __shfl_xor(ps, 32);
                        lsum = lsum * fac + ps;
                        #pragma unroll
                        for (int i2 = 0; i2 < 4; i2++)
                            o[i2] *= __shfl(fac, g * 4 + i2);
                        // transpose P (C-layout of S^T) to A-frag via shfl
                        float pe[8];
                        #pragma unroll
                        for (int e = 0; e < 8; e++) {
                            int src = ((g & 1) * 2 + (e >> 2)) * 16 + cl;
                            float a0 = __shfl(p0[e & 3], src);
                            float a1 = __shfl(p1[e & 3], src);
                            pe[e] = (g >> 1) ? a1 : a0;
                        }
                        union { unsigned u[4]; s8v v; } pu;
                        #pragma unroll
                        for (int j = 0; j < 4; j++)
                            pu.u[j] = (unsigned)f2bf(pe[2 * j]) |
                                      ((unsigned)f2bf(pe[2 * j + 1]) << 16);
                        s8v vf = *(const s8v*)(vb + ((headl * 4 + kt) * 4 + g) * 64
                                               + (cl & 7) * 8);
                        o = mfma16(pu.v, vf, o);
                        m = nm;
                    }
                    float inv = 1.f / lsum;
                    float invt[4];
                    #pragma unroll
                    for (int i2 = 0; i2 < 4; i2++) invt[i2] = __shfl(inv, g * 4 + i2);
                    unsigned pk0 = (unsigned)f2bf(o[0] * invt[0]) |
                                   ((unsigned)f2bf(o[1] * invt[1]) << 16);
                    unsigned pk1 = (unsigned)f2bf(o[2] * invt[2]) |
                                   ((unsigned)f2bf(o[3] * invt[3]) << 16);
                    if (hf == 0) {                      // per-lane register stash
                        switch (ti) {
                            case 0:  st0a = pk0; st0b = pk1; break;
                            case 1:  st1a = pk0; st1b = pk1; break;
                            case 2:  st2a = pk0; st2b = pk1; break;
                            default: st3a = pk0; st3b = pk1; break;
                        }
                    } else {
                        store_o(xah, mt, 4 + headl, g, cl, pk0, pk1);
                    }
                }
                if (hf == 1) {                          // flush half-0 outputs now
                    int t0 = w, t1 = w + 8, t2 = w + 16, t3 = w + 24;
                    store_o(xah, t0 >> 2, t0 & 3, g, cl, st0a, st0b);
                    store_o(xah, t1 >> 2, t1 & 3, g, cl, st1a, st1b);
                    store_o(xah, t2 >> 2, t2 & 3, g, cl, st2a, st2b);
                    store_o(xah, t3 >> 2, t3 & 3, g, cl, st3a, st3b);
                }
            }
            __syncthreads();
        }

        // ---- WO: 32 tiles, 4/wave; D += xs + bo ----
        {
            const unsigned short* pbase = pkw + 36864 + lay * 4096;
            const float* bo = W + OFF_BO + lay * 64;
            #pragma unroll 1
            for (int i = 0; i < 4; i++) {
                int ft = w * 4 + i;
                int mt = ft >> 2, nt = ft & 3;
                const unsigned short* pb = pbase + nt * 1024 + lane * 8;
                f4v acc = {0.f, 0.f, 0.f, 0.f};
                #pragma unroll
                for (int kt = 0; kt < 2; kt++) {
                    s8v ah = *(const s8v*)(xah + ((mt * 2 + kt) * 64 + lane) * 8);
                    s8v bh = *(const s8v*)(pb + kt * 512);
                    s8v bl = *(const s8v*)(pb + PKLO + kt * 512);
                    acc = mfma16(ah, bh, acc);
                    acc = mfma16(ah, bl, acc);
                }
                int row0 = mt * 16 + g * 4, col = nt * 16 + cl;
                float bias = bo[col];
                #pragma unroll
                for (int i2 = 0; i2 < 4; i2++)
                    xs[row0 + i2][col] += acc[i2] + bias;
            }
        }
        __syncthreads();

        ln_frag_hi(xs, xah, W + OFF_LN2G + lay * 64, W + OFF_LN2B + lay * 64, tid);
        ln_frag_hi(xs, xah, W + OFF_LN2G + lay * 64, W + OFF_LN2B + lay * 64, tid + 512);
        __syncthreads();

        // ---- FFN: 4 chunks of 32 rows; hidden bf16-hi in uni ----
        #pragma unroll 1
        for (int ch = 0; ch < 4; ch++) {
            {   // F1: 32 tiles, 4/wave
                const float* b1 = W + OFF_B1 + lay * 256;
                #pragma unroll 1
                for (int i = 0; i < 4; i++) {
                    int ft = w * 4 + i;
                    int mtl = ft >> 4, nt = ft & 15;
                    int mtg = ch * 2 + mtl;
                    const unsigned short* pb = pkw + 49152 + lay * 16384 + nt * 1024 + lane * 8;
                    f4v acc = {0.f, 0.f, 0.f, 0.f};
                    #pragma unroll
                    for (int kt = 0; kt < 2; kt++) {
                        s8v ah = *(const s8v*)(xah + ((mtg * 2 + kt) * 64 + lane) * 8);
                        s8v bh = *(const s8v*)(pb + kt * 512);
                        s8v bl = *(const s8v*)(pb + PKLO + kt * 512);
                        acc = mfma16(ah, bh, acc);
                        acc = mfma16(ah, bl, acc);
                    }
                    int col = nt * 16 + cl;
                    float bias = b1[col];
                    int kt2 = col >> 5, q2 = (col >> 3) & 3, e2 = col & 7;
                    #pragma unroll
                    for (int i2 = 0; i2 < 4; i2++) {
                        int lr = mtl * 16 + g * 4 + i2;
                        float hv = fmaxf(acc[i2] + bias, 0.f);
                        ha[((mtl * 8 + kt2) * 64 + q2 * 16 + (lr & 15)) * 8 + e2] = f2bf(hv);
                    }
                }
            }
            __syncthreads();
            {   // F2: 8 tiles, 1/wave (all 8 waves busy); K=256
                const float* b2 = W + OFF_B2 + lay * 64;
                int mtl = w >> 2, nt = w & 3;
                const unsigned short* pb = pkw + 98304 + lay * 16384 + nt * 4096 + lane * 8;
                f4v acc = {0.f, 0.f, 0.f, 0.f};
                #pragma unroll 2
                for (int kt = 0; kt < 8; kt++) {
                    s8v ah = *(const s8v*)(ha + ((mtl * 8 + kt) * 64 + lane) * 8);
                    s8v bh = *(const s8v*)(pb + kt * 512);
                    s8v bl = *(const s8v*)(pb + PKLO + kt * 512);
                    acc = mfma16(ah, bh, acc);
                    acc = mfma16(ah, bl, acc);
                }
                int row0 = ch * 32 + mtl * 16 + g * 4, col = nt * 16 + cl;
                float bias = b2[col];
                #pragma unroll
                for (int i2 = 0; i2 < 4; i2++)
                    xs[row0 + i2][col] += acc[i2] + bias;
            }
            __syncthreads();
        }
    }

    // ---- final LN -> xah (bf16-hi frags) ----
    ln_frag_hi(xs, xah, W + OFF_LNFG, W + OFF_LNFB, tid);
    ln_frag_hi(xs, xah, W + OFF_LNFG, W + OFF_LNFB, tid + 512);
    __syncthreads();

    // ---- logits via MFMA (all 8 waves), softmax + loss in C-layout ----
    {
        int mt = w;
        const unsigned short* pb = pkw + 147456 + lane * 8;
        f4v acc[4];
        #pragma unroll
        for (int nt = 0; nt < 4; nt++) {
            f4v a = {0.f, 0.f, 0.f, 0.f};
            #pragma unroll
            for (int kt = 0; kt < 2; kt++) {
                s8v ah = *(const s8v*)(xah + ((mt * 2 + kt) * 64 + lane) * 8);
                s8v bh = *(const s8v*)(pb + nt * 1024 + kt * 512);
                s8v bl = *(const s8v*)(pb + PKLO + nt * 1024 + kt * 512);
                a = mfma16(ah, bh, a);
                a = mfma16(ah, bl, a);
            }
            float bias = W[OFF_LMB + nt * 16 + cl];
            #pragma unroll
            for (int i2 = 0; i2 < 4; i2++) a[i2] += bias;
            acc[nt] = a;
        }
        // column 64 (row = mt*16+cl): partial dot over dims g*16..g*16+15
        float l2 = 0.f;
        #pragma unroll
        for (int j = 0; j < 16; j++) {
            int d = g * 16 + j;
            int xi = ((mt * 2 + (d >> 5)) * 64 + ((d >> 3) & 3) * 16 + cl) * 8 + (d & 7);
            l2 += bf2f(xah[xi]) * W[OFF_LMW + d * 65 + 64];
        }
        l2 += __shfl_xor(l2, 16);
        l2 += __shfl_xor(l2, 32);
        l2 += W[OFF_LMB + 64];
        float l2t[4];
        #pragma unroll
        for (int i2 = 0; i2 < 4; i2++) l2t[i2] = __shfl(l2, g * 4 + i2);

        float wacc = 0.f;
        #pragma unroll
        for (int i2 = 0; i2 < 4; i2++) {
            float M = fmaxf(fmaxf(acc[0][i2], acc[1][i2]), fmaxf(acc[2][i2], acc[3][i2]));
            M = fmaxf(M, __shfl_xor(M, 1)); M = fmaxf(M, __shfl_xor(M, 2));
            M = fmaxf(M, __shfl_xor(M, 4)); M = fmaxf(M, __shfl_xor(M, 8));
            M = fmaxf(M, l2t[i2]);
            float ss = __expf(acc[0][i2] - M) + __expf(acc[1][i2] - M)
                     + __expf(acc[2][i2] - M) + __expf(acc[3][i2] - M);
            ss += __shfl_xor(ss, 1); ss += __shfl_xor(ss, 2);
            ss += __shfl_xor(ss, 4); ss += __shfl_xor(ss, 8);
            ss += __expf(l2t[i2] - M);
            float lse = M + logf(ss);
            int r = mt * 16 + g * 4 + i2;
            int row = b * NT + r;
            int tg = i64 ? (int)tgt64[row] : tgt32[row];
            float lt = 0.f;
            #pragma unroll
            for (int nt = 0; nt < 4; nt++)
                if (nt * 16 + cl == tg) lt += acc[nt][i2];
            wacc += lt;
            if (cl == 0) {
                if (tg == 64) wacc += l2t[i2];
                wacc -= lse;
                out[row * NV + 64] = l2t[i2];
            }
            #pragma unroll
            for (int nt = 0; nt < 4; nt++)
                out[row * NV + nt * 16 + cl] = acc[nt][i2];
        }
        wacc += __shfl_xor(wacc, 1);  wacc += __shfl_xor(wacc, 2);
        wacc += __shfl_xor(wacc, 4);  wacc += __shfl_xor(wacc, 8);
        wacc += __shfl_xor(wacc, 16); wacc += __shfl_xor(wacc, 32);
        if (lane == 0) wsum[w] = wacc;
    }
    __syncthreads();
    if (tid == 0) {
        float t = 0.f;
        #pragma unroll
        for (int wv = 0; wv < 8; wv++) t += wsum[wv];
        atomicAdd(loss_acc, t);
    }
    __syncthreads();

    // ---- self-check: block 0 thread 0 recomputes row 0 logits (attn = v0) ----
    if (b == 0 && tid == 0) {
        float x0[ND], xn0[ND], v0[ND], h0[NDF];
        int tok0 = i64 ? (int)idx64[0] : idx32[0];
        for (int c = 0; c < ND; c++)
            x0[c] = W[OFF_TOK + tok0 * ND + c] + W[OFF_POS + c];
        for (int l = 0; l < NL; l++) {
            ln_scalar(x0, xn0, W + OFF_LN1G + l * ND, W + OFF_LN1B + l * ND);
            for (int c = 0; c < ND; c++) {
                float a = 0.f;
                for (int i = 0; i < ND; i++)
                    a += xn0[i] * W[OFF_WV + l * ND * ND + i * ND + c];
                v0[c] = a;
            }
            for (int c = 0; c < ND; c++) {
                float a = W[OFF_BO + l * ND + c];
                for (int i = 0; i < ND; i++)
                    a += v0[i] * W[OFF_WO + l * ND * ND + i * ND + c];
                x0[c] += a;
            }
            ln_scalar(x0, xn0, W + OFF_LN2G + l * ND, W + OFF_LN2B + l * ND);
            for (int j = 0; j < NDF; j++) {
                float a = W[OFF_B1 + l * NDF + j];
                for (int i = 0; i < ND; i++)
                    a += xn0[i] * W[OFF_W1 + l * ND * NDF + i * NDF + j];
                h0[j] = fmaxf(a, 0.f);
            }
            for (int c = 0; c < ND; c++) {
                float a = W[OFF_B2 + l * ND + c];
                for (int j = 0; j < NDF; j++)
                    a += h0[j] * W[OFF_W2 + l * NDF * ND + j * ND + c];
                x0[c] += a;
            }
        }
        ln_scalar(x0, xn0, W + OFF_LNFG, W + OFF_LNFB);
        bool bad = false;
        for (int v = 0; v < NV; v++) {
            float lg = W[OFF_LMB + v];
            for (int i = 0; i < ND; i++)
                lg += xn0[i] * W[OFF_LMW + i * NV + v];
            if (!(fabsf(out[v] - lg) <= 0.1f)) bad = true;   // catches NaN
        }
        if (bad) out[0] = 100.0f;
    }
}

// ======================= VALU fallback kernel (round-1, known good) =======================
__global__ __launch_bounds__(1024, 4) void gpt_fwd_valu(
    const float* __restrict__ W, int usepk,
    const void* __restrict__ idxp, const void* __restrict__ tgtp,
    float* __restrict__ out, float* __restrict__ loss_acc,
    const int* __restrict__ flags)
{
    const int fl = *flags;
    if (usepk && !(fl & 8)) return;                    // main kernel handled it

    __shared__ alignas(16) float xs[NT][68];
    __shared__ alignas(16) float xn[NT][68];
    __shared__ alignas(16) unsigned short qs[NT][72];
    __shared__ alignas(16) unsigned short ks[NT][72];
    __shared__ alignas(16) unsigned short vs[NT][72];
    __shared__ alignas(16) float hch[32][264];
    __shared__ float wsum[16];

    const int tid  = threadIdx.x;
    const int lane = tid & 63;
    const int w    = tid >> 6;
    const int b    = blockIdx.x;
    const bool i64 = !(fl & 4);
    const int*       idx32 = (const int*)idxp;
    const long long* idx64 = (const long long*)idxp;
    const int*       tgt32 = (const int*)tgtp;
    const long long* tgt64 = (const long long*)tgtp;

    for (int e = tid * 4; e < NT * ND; e += 4096) {
        int r = e >> 6, c = e & 63;
        int n = b * NT + r;
        int tok = i64 ? (int)idx64[n] : idx32[n];
        float4 te = *(const float4*)&W[OFF_TOK + tok * ND + c];
        float4 pe = *(const float4*)&W[OFF_POS + r * ND + c];
        float4 xv;
        xv.x = te.x + pe.x; xv.y = te.y + pe.y;
        xv.z = te.z + pe.z; xv.w = te.w + pe.w;
        *(float4*)&xs[r][c] = xv;
    }
    __syncthreads();

    for (int lay = 0; lay < NL; lay++) {
        ln_rm(xs, xn, W + OFF_LN1G + lay * 64, W + OFF_LN1B + lay * 64, tid);
        __syncthreads();
        {
            #pragma unroll 1
            for (int mmat = 0; mmat < 3; mmat++) {
                const float* wm = W + (mmat == 0 ? OFF_WQ : (mmat == 1 ? OFF_WK : OFF_WV))
                                    + lay * ND * ND;
                unsigned short (*dstp)[72] = (mmat == 0) ? qs : ((mmat == 1) ? ks : vs);
                float acc[8];
                #pragma unroll
                for (int rr = 0; rr < 8; rr++) acc[rr] = 0.f;
                #pragma unroll 1
                for (int ih = 0; ih < 4; ih++) {
                    float wr[16];
                    #pragma unroll
                    for (int i = 0; i < 16; i++) wr[i] = wm[(ih * 16 + i) * ND + lane];
                    #pragma unroll
                    for (int rr = 0; rr < 8; rr++)
                        fma16(&xn[w * 8 + rr][ih * 16], wr, acc[rr]);
                }
                #pragma unroll
                for (int rr = 0; rr < 8; rr++)
                    dstp[w * 8 + rr][lane] = f2bf(acc[rr]);
            }
        }
        __syncthreads();
        {
            const int head = w & 7, hh = w >> 3;
            const int h8 = head * 8;
            const int r  = lane + hh * 64;
            const float scale = 0.35355339059327373f;
            float qv[8];
            uint4 qq = *(const uint4*)&qs[r][h8];
            unpack8(qq, qv);
            #pragma unroll
            for (int d = 0; d < 8; d++) qv[d] *= scale;
            float m = -1e30f, lsum = 0.f;
            float o[8] = {0, 0, 0, 0, 0, 0, 0, 0};
            for (int base = 0; base <= r; base += 8) {
                float sc[8];
                #pragma unroll
                for (int t = 0; t < 8; t++) {
                    int kk = base + t; kk = kk > 127 ? 127 : kk;
                    uint4 kr = *(const uint4*)&ks[kk][h8];
                    float kf[8]; unpack8(kr, kf);
                    float s = 0.f;
                    #pragma unroll
                    for (int d = 0; d < 8; d++) s = fmaf(qv[d], kf[d], s);
                    sc[t] = (base + t <= r) ? s : -1e30f;
                }
                float cm = fmaxf(fmaxf(fmaxf(sc[0], sc[1]), fmaxf(sc[2], sc[3])),
                                 fmaxf(fmaxf(sc[4], sc[5]), fmaxf(sc[6], sc[7])));
                float nm  = fmaxf(m, cm);
                float fac = __expf(m - nm);
                lsum *= fac;
                #pragma unroll
                for (int d = 0; d < 8; d++) o[d] *= fac;
                #pragma unroll
                for (int t = 0; t < 8; t++) {
                    float p = __expf(sc[t] - nm);
                    int kk = base + t; kk = kk > 127 ? 127 : kk;
                    uint4 vr = *(const uint4*)&vs[kk][h8];
                    float vf[8]; unpack8(vr, vf);
                    lsum += p;
                    #pragma unroll
                    for (int d = 0; d < 8; d++) o[d] = fmaf(p, vf[d], o[d]);
                }
                m = nm;
            }
            float inv = 1.f / lsum;
            #pragma unroll
            for (int d = 0; d < 8; d++) xn[r][h8 + d] = o[d] * inv;
        }
        __syncthreads();
        {
            const float* wo = W + OFF_WO + lay * ND * ND;
            float acc[8];
            #pragma unroll
            for (int rr = 0; rr < 8; rr++) acc[rr] = W[OFF_BO + lay * ND + lane];
            #pragma unroll 1
            for (int ih = 0; ih < 4; ih++) {
                float wr[16];
                #pragma unroll
                for (int i = 0; i < 16; i++) wr[i] = wo[(ih * 16 + i) * ND + lane];
                #pragma unroll
                for (int rr = 0; rr < 8; rr++)
                    fma16(&xn[w * 8 + rr][ih * 16], wr, acc[rr]);
            }
            #pragma unroll
            for (int rr = 0; rr < 8; rr++)
                xs[w * 8 + rr][lane] += acc[rr];
        }
        __syncthreads();
        ln_rm(xs, xn, W + OFF_LN2G + lay * 64, W + OFF_LN2B + lay * 64, tid);
        __syncthreads();
        {
            const float* w1 = W + OFF_W1 + lay * ND * NDF;
            const float* w2 = W + OFF_W2 + lay * NDF * ND;
            const float* b1 = W + OFF_B1 + lay * NDF;
            const float* b2 = W + OFF_B2 + lay * ND;
            for (int ch = 0; ch < 4; ch++) {
                int rbase = ch * 32;
                {
                    int lr = tid >> 5;
                    int j0 = (tid & 31) * 8;
                    int r  = rbase + lr;
                    float4 ba  = *(const float4*)(b1 + j0);
                    float4 bb4 = *(const float4*)(b1 + j0 + 4);
                    float a0 = ba.x,  a1 = ba.y,  a2 = ba.z,  a3 = ba.w;
                    float a4 = bb4.x, a5 = bb4.y, a6 = bb4.z, a7 = bb4.w;
                    #pragma unroll 4
                    for (int i4 = 0; i4 < ND; i4 += 4) {
                        float4 xv = *(const float4*)&xn[r][i4];
                        #pragma unroll
                        for (int s = 0; s < 4; s++) {
                            float xvs = (s == 0) ? xv.x : (s == 1) ? xv.y
                                      : (s == 2) ? xv.z : xv.w;
                            float4 wa = *(const float4*)(w1 + (i4 + s) * NDF + j0);
                            float4 wb = *(const float4*)(w1 + (i4 + s) * NDF + j0 + 4);
                            a0 = fmaf(xvs, wa.x, a0); a1 = fmaf(xvs, wa.y, a1);
                            a2 = fmaf(xvs, wa.z, a2); a3 = fmaf(xvs, wa.w, a3);
                            a4 = fmaf(xvs, wb.x, a4); a5 = fmaf(xvs, wb.y, a5);
                            a6 = fmaf(xvs, wb.z, a6); a7 = fmaf(xvs, wb.w, a7);
                        }
                    }
                    float4 h0v, h1v;
                    h0v.x = fmaxf(a0, 0.f); h0v.y = fmaxf(a1, 0.f);
                    h0v.z = fmaxf(a2, 0.f); h0v.w = fmaxf(a3, 0.f);
                    h1v.x = fmaxf(a4, 0.f); h1v.y = fmaxf(a5, 0.f);
                    h1v.z = fmaxf(a6, 0.f); h1v.w = fmaxf(a7, 0.f);
                    *(float4*)&hch[lr][j0]     = h0v;
                    *(float4*)&hch[lr][j0 + 4] = h1v;
                }
                __syncthreads();
                {
                    int lr = tid >> 5;
                    int i0 = (tid & 31) * 2;
                    int r  = rbase + lr;
                    float a0 = 0.f, a1 = 0.f;
                    #pragma unroll 4
                    for (int j4 = 0; j4 < NDF; j4 += 4) {
                        float4 hv = *(const float4*)&hch[lr][j4];
                        #pragma unroll
                        for (int s = 0; s < 4; s++) {
                            float hvs = (s == 0) ? hv.x : (s == 1) ? hv.y
                                      : (s == 2) ? hv.z : hv.w;
                            float2 w2v = *(const float2*)(w2 + (j4 + s) * ND + i0);
                            a0 = fmaf(hvs, w2v.x, a0); a1 = fmaf(hvs, w2v.y, a1);
                        }
                    }
                    float2 bb2 = *(const float2*)(b2 + i0);
                    xs[r][i0]     += a0 + bb2.x;
                    xs[r][i0 + 1] += a1 + bb2.y;
                }
                __syncthreads();
            }
        }
    }
    ln_rm(xs, xn, W + OFF_LNFG, W + OFF_LNFB, tid);
    __syncthreads();

    {
        const float* lmw = W + OFF_LMW;
        float wacc = 0.f;
        for (int rr = 0; rr < 8; rr++) {
            int r = w * 8 + rr;
            float lg  = W[OFF_LMB + lane];
            float lg2 = W[OFF_LMB + 64];
            #pragma unroll 8
            for (int i = 0; i < ND; i++) {
                float xv = xn[r][i];
                lg  = fmaf(xv, lmw[i * NV + lane], lg);
                lg2 = fmaf(xv, lmw[i * NV + 64],  lg2);
            }
            float M = lg;
            #pragma unroll
            for (int off = 32; off; off >>= 1) M = fmaxf(M, __shfl_xor(M, off));
            M = fmaxf(M, lg2);
            float ssum = __expf(lg - M);
            #pragma unroll
            for (int off = 32; off; off >>= 1) ssum += __shfl_xor(ssum, off);
            ssum += __expf(lg2 - M);
            float lse = M + logf(ssum);
            int row = b * NT + r;
            int tg  = i64 ? (int)tgt64[row] : tgt32[row];
            float lt = (tg < 64) ? __shfl(lg, tg) : lg2;
            wacc += lt - lse;
            out[row * NV + lane] = lg;
            if (lane == 0) out[row * NV + 64] = lg2;
        }
        if (lane == 0) wsum[w] = wacc;
        __syncthreads();
        if (tid == 0) {
            float t = 0.f;
            #pragma unroll
            for (int wv = 0; wv < 16; wv++) t += wsum[wv];
            atomicAdd(loss_acc, t);
        }
    }
}

__global__ void finalize_loss(const float* __restrict__ acc,
                              float* __restrict__ out) {
    out[NBT * NV] = -acc[0] * (1.f / (float)NBT);
}

extern "C" void kernel_launch(void* const* d_in, const int* in_sizes, int n_in,
                              void* d_out, int out_size, void* d_ws, size_t ws_size,
                              hipStream_t stream)
{
    static const int want[21] = {4160, 8192, 192, 192, 12288, 12288, 12288,
                                 12288, 192, 192, 192, 49152, 768, 49152, 192,
                                 64, 64, 4160, 65, 524288, 524288};
    int diag = 0;
    if (n_in != 21) diag = 3;
    else for (int i = 0; i < 21; i++) if (in_sizes[i] != want[i]) { diag = 3; break; }
    if (!diag && out_size != NBT * NV + 1) diag = 4;
    if (!diag && ws_size < (size_t)(OFF_FLAG + 1) * 4) diag = 5;
    if (diag) {
        diag_fill<<<(out_size + 255) / 256, 256, 0, stream>>>(
            (float*)d_out, out_size, (float)diag);
        return;
    }

    float* W = (float*)d_ws;
    float* loss_acc = W + OFF_LOSS;
    int*   flags    = (int*)(W + OFF_FLAG);
    hipMemsetAsync(W + OFF_LOSS, 0, 2 * sizeof(float), stream);

    detect_float<<<1, 256, 0, stream>>>((const unsigned short*)d_in[0], flags);
    detect_int  <<<1, 256, 0, stream>>>((const int*)d_in[19], flags);
    mfma_probe  <<<1, 64,  0, stream>>>(flags);

    CvtArgs a;
    for (int i = 0; i < 19; i++) a.p[i] = d_in[i];
    cvt_params<<<(CVT_TOTAL + 255) / 256, 256, 0, stream>>>(a, W, flags);

    int usepk = (ws_size >= NEED_WS) ? 1 : 0;
    unsigned short* pkw = (unsigned short*)(W + PKF);
    if (usepk)
        pack_weights<<<(PK_ELEMS + 255) / 256, 256, 0, stream>>>(W, pkw);

    gpt_fwd<<<NB, 512, 0, stream>>>(W, pkw, usepk, d_in[19], d_in[20],
                                    (float*)d_out, loss_acc, flags);
    gpt_fwd_valu<<<NB, 1024, 0, stream>>>(W, usepk, d_in[19], d_in[20],
                                          (float*)d_out, loss_acc, flags);
    finalize_loss<<<1, 1, 0, stream>>>(loss_acc, (float*)d_out);
}

// Round 9
// 2549.383 us; speedup vs baseline: 1.0625x; 1.0625x over previous
//
#include <hip/hip_runtime.h>
#include <hip/hip_bf16.h>

#define NB  4096
#define NT  128
#define ND  64
#define NV  65
#define NL  3
#define NH  8
#define NDF 256
#define NBT (NB*NT)

// fp32 param offsets inside d_ws (element counts)
#define OFF_TOK   0
#define OFF_POS   4160
#define OFF_LN1G  12352
#define OFF_LN1B  12544
#define OFF_WQ    12736
#define OFF_WK    25024
#define OFF_WV    37312
#define OFF_WO    49600
#define OFF_BO    61888
#define OFF_LN2G  62080
#define OFF_LN2B  62272
#define OFF_W1    62464
#define OFF_B1    111616
#define OFF_W2    112384
#define OFF_B2    161536
#define OFF_LNFG  161728
#define OFF_LNFB  161792
#define OFF_LMW   161856
#define OFF_LMB   166016
#define CVT_TOTAL 166081
#define OFF_LOSS  166144   // fp32 loss accumulator slot
#define OFF_FLAG  166145   // flags: bit0 fp32 floats; bit2 int32 ints; bit3 MFMA-layout-BAD

// packed bf16 weights (hi + lo) appended after flag
#define PKF       166148            // float offset of packed region
#define PK_ELEMS  151552            // bf16 elements (hi); lo mirrors at +PK_ELEMS
#define PKLO      151552
#define NEED_WS   ((size_t)(PKF + PK_ELEMS) * 4)

typedef short s8v  __attribute__((ext_vector_type(8)));
typedef float f4v  __attribute__((ext_vector_type(4)));

struct CvtArgs { const void* p[19]; };

__device__ __forceinline__ unsigned short f2bf(float x) {
    unsigned int u = __float_as_uint(x);
    u = (u + 0x7fffu + ((u >> 16) & 1u)) >> 16;   // RNE
    return (unsigned short)u;
}
__device__ __forceinline__ float bf2f(unsigned short h) {
    return __uint_as_float(((unsigned int)h) << 16);
}
__device__ __forceinline__ f4v mfma16(s8v a, s8v b, f4v c) {
    return __builtin_amdgcn_mfma_f32_16x16x32_bf16(a, b, c, 0, 0, 0);
}

__global__ void diag_fill(float* __restrict__ out, int n, float val) {
    int i = blockIdx.x * 256 + threadIdx.x;
    if (i < n) out[i] = val;
}

__global__ void detect_float(const unsigned short* __restrict__ tok,
                             int* __restrict__ flags) {
    int bad = 0;
    for (int i = threadIdx.x; i < 4096; i += 256) {
        float v = __uint_as_float(((unsigned int)tok[i]) << 16);
        if (!(fabsf(v) < 1000.f)) bad = 1;
    }
    if (bad) atomicOr(flags, 1);
}

__global__ void detect_int(const int* __restrict__ idx32,
                           int* __restrict__ flags) {
    int proven = 0;
    #pragma unroll
    for (int j = 0; j < 8; j++) {
        int slot = 2 * (threadIdx.x * 8 + j) + 1;
        if (idx32[slot] != 0) proven = 1;
    }
    if (proven) atomicOr(flags, 4);
}

// param conversion (bf16 or fp32 -> fp32) into workspace
__global__ void cvt_params(CvtArgs a, float* __restrict__ W,
                           const int* __restrict__ flags) {
    int tid = blockIdx.x * 256 + threadIdx.x;
    if (tid >= CVT_TOTAL) return;
    const int offs[20] = {0,4160,12352,12544,12736,25024,37312,49600,61888,
                          62080,62272,62464,111616,112384,161536,161728,
                          161792,161856,166016,166081};
    int s = 0;
    #pragma unroll
    for (int k = 1; k < 19; k++) s += (tid >= offs[k]);
    int local = tid - offs[s];
    if (*flags & 1) {
        W[tid] = ((const float*)a.p[s])[local];
    } else {
        unsigned int v = ((const unsigned short*)a.p[s])[local];
        W[tid] = __uint_as_float(v << 16);
    }
}

// Pack matmul weights into MFMA b-frag order, hi+lo bf16.
// B-frag: lane l elem e holds B[kt*32 + (l>>4)*8 + e][nt*16 + (l&15)]
__global__ void pack_weights(const float* __restrict__ W,
                             unsigned short* __restrict__ pkw) {
    int p = blockIdx.x * 256 + threadIdx.x;
    if (p >= PK_ELEMS) return;
    int srcoff, K, N, perlay, local, ktbits;
    if (p < 49152) {
        int grp = p / 12288; local = p % 12288;
        srcoff = (grp == 0) ? OFF_WQ : (grp == 1) ? OFF_WK
               : (grp == 2) ? OFF_WV : OFF_WO;
        K = 64; N = 64; perlay = 4096; ktbits = 1;
    } else if (p < 98304) {
        local = p - 49152; srcoff = OFF_W1; K = 64; N = 256;
        perlay = 16384; ktbits = 1;
    } else if (p < 147456) {
        local = p - 98304; srcoff = OFF_W2; K = 256; N = 64;
        perlay = 16384; ktbits = 3;
    } else {
        local = p - 147456; srcoff = OFF_LMW; K = 64; N = 65;   // lm head, cols 0..63
        perlay = 4096; ktbits = 1;
    }
    int lay = local / perlay, rem = local % perlay;
    int t = rem >> 9, le = rem & 511, l = le >> 3, e = le & 7;
    int kt = t & ((1 << ktbits) - 1), nt = t >> ktbits;
    int row = kt * 32 + (l >> 4) * 8 + e;
    int col = nt * 16 + (l & 15);
    float v = W[srcoff + lay * K * N + row * N + col];
    unsigned short hi = f2bf(v);
    pkw[p] = hi;
    pkw[PKLO + p] = f2bf(v - bf2f(hi));
}

// Verify A/B operand layout vs HW-verified C/D layout (asymmetric ints).
__global__ void mfma_probe(int* __restrict__ flags) {
    int l = threadIdx.x;
    s8v av, bv;
    int i = l & 15;
    #pragma unroll
    for (int e = 0; e < 8; e++) {
        int k = (l >> 4) * 8 + e;
        av[e] = (short)f2bf((float)(((i * 5 + k * 3) & 7) - 3));
        bv[e] = (short)f2bf((float)(((k * 7 + i * 11) & 7) - 4));
    }
    f4v c = {0.f, 0.f, 0.f, 0.f};
    c = mfma16(av, bv, c);
    int bad = 0;
    #pragma unroll
    for (int reg = 0; reg < 4; reg++) {
        int row = (l >> 4) * 4 + reg, col = l & 15;
        float exp = 0.f;
        for (int k = 0; k < 32; k++)
            exp += (float)(((row * 5 + k * 3) & 7) - 3) *
                   (float)(((k * 7 + col * 11) & 7) - 4);
        if (c[reg] != exp) bad = 1;
    }
    if (bad) atomicOr(flags, 8);
}

__device__ __forceinline__ void unpack8(uint4 u, float* f) {
    f[0] = __uint_as_float(u.x << 16); f[1] = __uint_as_float(u.x & 0xffff0000u);
    f[2] = __uint_as_float(u.y << 16); f[3] = __uint_as_float(u.y & 0xffff0000u);
    f[4] = __uint_as_float(u.z << 16); f[5] = __uint_as_float(u.z & 0xffff0000u);
    f[6] = __uint_as_float(u.w << 16); f[7] = __uint_as_float(u.w & 0xffff0000u);
}

// LayerNorm over D=64, 8 threads/row, fp32 row-major out (VALU path helper)
__device__ __forceinline__ void ln_rm(const float (*src)[68], float (*dst)[68],
                                      const float* __restrict__ g,
                                      const float* __restrict__ bb, int tid) {
    int r = tid >> 3, q = tid & 7;
    int c0 = q * 8;
    float s = 0.f, s2 = 0.f;
    #pragma unroll
    for (int c = 0; c < 8; c++) { float v = src[r][c0 + c]; s += v; s2 += v * v; }
    s += __shfl_xor(s, 1);  s2 += __shfl_xor(s2, 1);
    s += __shfl_xor(s, 2);  s2 += __shfl_xor(s2, 2);
    s += __shfl_xor(s, 4);  s2 += __shfl_xor(s2, 4);
    float mu   = s  * (1.f / 64.f);
    float var  = s2 * (1.f / 64.f) - mu * mu;
    float rstd = rsqrtf(var + 1e-5f);
    #pragma unroll
    for (int c = 0; c < 8; c++) {
        int cc = c0 + c;
        dst[r][cc] = (src[r][cc] - mu) * rstd * g[cc] + bb[cc];
    }
}

// LayerNorm writing bf16-hi a-frag layout: elem (r,col) at
// (((r>>4)*2 + (col>>5))*64 + ((col>>3)&3)*16 + (r&15))*8 + (col&7)
__device__ __forceinline__ void ln_frag_hi(const float (*src)[68],
        unsigned short* __restrict__ dhi,
        const float* __restrict__ g, const float* __restrict__ bb, int tid) {
    int r = tid >> 3, q = tid & 7, c0 = q * 8;
    float s = 0.f, s2 = 0.f;
    #pragma unroll
    for (int c = 0; c < 8; c++) { float v = src[r][c0 + c]; s += v; s2 += v * v; }
    s += __shfl_xor(s, 1);  s2 += __shfl_xor(s2, 1);
    s += __shfl_xor(s, 2);  s2 += __shfl_xor(s2, 2);
    s += __shfl_xor(s, 4);  s2 += __shfl_xor(s2, 4);
    float mu   = s  * (1.f / 64.f);
    float var  = s2 * (1.f / 64.f) - mu * mu;
    float rstd = rsqrtf(var + 1e-5f);
    unsigned uh[4];
    #pragma unroll
    for (int c2 = 0; c2 < 4; c2++) {
        float y0 = (src[r][c0 + c2*2    ] - mu) * rstd * g[c0 + c2*2    ] + bb[c0 + c2*2    ];
        float y1 = (src[r][c0 + c2*2 + 1] - mu) * rstd * g[c0 + c2*2 + 1] + bb[c0 + c2*2 + 1];
        uh[c2] = (unsigned)f2bf(y0) | ((unsigned)f2bf(y1) << 16);
    }
    int di = (((r >> 4) * 2 + (q >> 2)) * 64 + (q & 3) * 16 + (r & 15)) * 8;
    *(uint4*)(dhi + di) = make_uint4(uh[0], uh[1], uh[2], uh[3]);
}

// 16 FMAs of one activation row segment against cached weights (VALU path)
__device__ __forceinline__ void fma16(const float* xr, const float* wr, float& a) {
    float4 x0 = *(const float4*)(xr);
    float4 x1 = *(const float4*)(xr + 4);
    float4 x2 = *(const float4*)(xr + 8);
    float4 x3 = *(const float4*)(xr + 12);
    a = fmaf(x0.x, wr[0],  a); a = fmaf(x0.y, wr[1],  a);
    a = fmaf(x0.z, wr[2],  a); a = fmaf(x0.w, wr[3],  a);
    a = fmaf(x1.x, wr[4],  a); a = fmaf(x1.y, wr[5],  a);
    a = fmaf(x1.z, wr[6],  a); a = fmaf(x1.w, wr[7],  a);
    a = fmaf(x2.x, wr[8],  a); a = fmaf(x2.y, wr[9],  a);
    a = fmaf(x2.z, wr[10], a); a = fmaf(x2.w, wr[11], a);
    a = fmaf(x3.x, wr[12], a); a = fmaf(x3.y, wr[13], a);
    a = fmaf(x3.z, wr[14], a); a = fmaf(x3.w, wr[15], a);
}

// scalar LN for the self-check path
__device__ void ln_scalar(const float* x, float* o,
                          const float* g, const float* bb) {
    float mu = 0.f;
    for (int i = 0; i < ND; i++) mu += x[i];
    mu *= (1.f / 64.f);
    float var = 0.f;
    for (int i = 0; i < ND; i++) { float d = x[i] - mu; var += d * d; }
    var *= (1.f / 64.f);
    float rstd = rsqrtf(var + 1e-5f);
    for (int i = 0; i < ND; i++) o[i] = (x[i] - mu) * rstd * g[i] + bb[i];
}

// write one attention-output quad (packed bf16 pairs) into xah a-frag layout
__device__ __forceinline__ void store_o(unsigned short* xah, int mt, int head,
                                        int g, int cl, unsigned pk0, unsigned pk1) {
    if (cl < 8) {
        unsigned pk[2] = {pk0, pk1};
        #pragma unroll
        for (int i2 = 0; i2 < 4; i2++) {
            int r = mt * 16 + g * 4 + i2;
            int col = head * 8 + cl;
            unsigned v = pk[i2 >> 1];
            unsigned short hv = (unsigned short)((i2 & 1) ? (v >> 16) : (v & 0xffffu));
            int di = (((r >> 4) * 2 + (col >> 5)) * 64 + ((col >> 3) & 3) * 16
                      + (r & 15)) * 8 + (col & 7);
            xah[di] = hv;
        }
    }
}

// ======================= main MFMA kernel (R5 base + latency-chain fixes) ===========
// R8 lesson: dur tracks VALU-issue ~proportionally across R1-R8 -> per-instruction
// dependency latency (shfl=ds_bpermute ~60-120cyc in serial chains) is the limiter.
// Fix: two-pass attention (batch K-loads/MFMAs; ONE reduction; independent exps;
// static-unrolled PV with pipelined transposes) + unroll-2 on GEMM tile loops.
__global__ __launch_bounds__(1024, 4) void gpt_fwd(
    const float* __restrict__ W, const unsigned short* __restrict__ pkw,
    int usepk, const void* __restrict__ idxp, const void* __restrict__ tgtp,
    float* __restrict__ out, float* __restrict__ loss_acc,
    const int* __restrict__ flags)
{
    __shared__ alignas(16) float xs[NT][68];            // residual, 34816B
    __shared__ alignas(16) unsigned short xah[8192];    // A-frag hi, 16384B
    __shared__ alignas(16) unsigned short uni[12288];   // q/k/vb half OR hidden, 24576B
    __shared__ alignas(16) unsigned short zblk[8];      // 16B zeros
    __shared__ float wsum[8];

    unsigned short* q_l = uni;                          // [4][128][8]
    unsigned short* k_l = uni + 4096;                   // [4][128][8]
    unsigned short* vb  = uni + 8192;                   // [4][4kt][4g][8c][8e]
    unsigned short* ha  = uni;                          // FFN hidden chunk [2][8][64][8]

    const int tid  = threadIdx.x;
    const int lane = tid & 63;
    const int w    = tid >> 6;
    const int cl   = lane & 15;
    const int g    = lane >> 4;
    const int b    = blockIdx.x;
    const int fl   = *flags;
    if (!usepk || (fl & 8)) return;                     // fallback kernel will run
    const bool i64 = !(fl & 4);
    const int*       idx32 = (const int*)idxp;
    const long long* idx64 = (const long long*)idxp;
    const int*       tgt32 = (const int*)tgtp;
    const long long* tgt64 = (const long long*)tgtp;

    if (tid < 8) zblk[tid] = 0;

    // ---- embed: x = tok_emb[idx] + pos_emb ----
    for (int e = tid * 4; e < NT * ND; e += 4096) {
        int r = e >> 6, c = e & 63;
        int n = b * NT + r;
        int tok = i64 ? (int)idx64[n] : idx32[n];
        float4 te = *(const float4*)&W[OFF_TOK + tok * ND + c];
        float4 pe = *(const float4*)&W[OFF_POS + r * ND + c];
        float4 xv;
        xv.x = te.x + pe.x; xv.y = te.y + pe.y;
        xv.z = te.z + pe.z; xv.w = te.w + pe.w;
        *(float4*)&xs[r][c] = xv;
    }
    __syncthreads();

    for (int lay = 0; lay < NL; lay++) {
        ln_frag_hi(xs, xah, W + OFF_LN1G + lay * 64, W + OFF_LN1B + lay * 64, tid);
        __syncthreads();

        const int headl = w & 3;
        // half-0 attn-out stash: per-lane packed bf16 pairs, named registers
        unsigned st0a = 0, st0b = 0, st1a = 0, st1b = 0;

        #pragma unroll 1
        for (int hf = 0; hf < 2; hf++) {
            // ---- QKV half: 48 tiles, 3/wave; unroll 2 to overlap b-frag loads ----
            {
                const unsigned short* pbase = pkw + lay * 4096;
                #pragma unroll 2
                for (int i = 0; i < 3; i++) {
                    int ft = w * 3 + i;                 // 0..47
                    int mat = ft >> 4;
                    int mt  = (ft >> 1) & 7;
                    int ntg = hf * 2 + (ft & 1);
                    const unsigned short* pb = pbase + mat * 12288 + ntg * 1024 + lane * 8;
                    f4v acc = {0.f, 0.f, 0.f, 0.f};
                    #pragma unroll
                    for (int kt = 0; kt < 2; kt++) {
                        s8v ah = *(const s8v*)(xah + ((mt * 2 + kt) * 64 + lane) * 8);
                        s8v bh = *(const s8v*)(pb + kt * 512);
                        s8v bl = *(const s8v*)(pb + PKLO + kt * 512);
                        acc = mfma16(ah, bh, acc);
                        acc = mfma16(ah, bl, acc);
                    }
                    int row0 = mt * 16 + g * 4;
                    int fullcol = ntg * 16 + cl;
                    int hl2 = (fullcol >> 3) & 3;
                    int dim = fullcol & 7;
                    if (mat == 0) {
                        #pragma unroll
                        for (int i2 = 0; i2 < 4; i2++)
                            q_l[(hl2 * 128 + row0 + i2) * 8 + dim] =
                                f2bf(acc[i2] * 0.35355339059327373f);
                    } else if (mat == 1) {
                        #pragma unroll
                        for (int i2 = 0; i2 < 4; i2++)
                            k_l[(hl2 * 128 + row0 + i2) * 8 + dim] = f2bf(acc[i2]);
                    } else {
                        #pragma unroll
                        for (int i2 = 0; i2 < 4; i2++) {
                            int key = row0 + i2;
                            vb[((hl2 * 4 + (key >> 5)) * 4 + ((key >> 3) & 3)) * 64
                               + dim * 8 + (key & 7)] = f2bf(acc[i2]);
                        }
                    }
                }
            }
            __syncthreads();

            // ---- attention half: TWO-PASS S^T softmax PV ----
            // pass1: all K-loads + QK^T MFMAs (independent, pipelined);
            // one max/sum reduction (2 shfls each); exp all (independent);
            // PV: static-unrolled kt with independent transposes.
            {
                #pragma unroll 1
                for (int ti = 0; ti < 2; ti++) {
                    int mt = (w >> 2) + ti * 4;
                    const unsigned short* qsrc = (lane < 16)
                        ? q_l + (headl * 128 + mt * 16 + cl) * 8 : zblk;
                    s8v qb = *(const s8v*)qsrc;
                    f4v sv[8];
                    // pass 1: S^T tiles (C row = key-in-tile, col = query cl)
                    #pragma unroll
                    for (int nt = 0; nt < 8; nt++) {
                        sv[nt] = (f4v){-1e30f, -1e30f, -1e30f, -1e30f};
                        if (nt <= mt) {
                            const unsigned short* ksrc = (lane < 16)
                                ? k_l + (headl * 128 + nt * 16 + cl) * 8 : zblk;
                            s8v kb = *(const s8v*)ksrc;
                            f4v s0 = {0.f, 0.f, 0.f, 0.f};
                            s0 = mfma16(kb, qb, s0);
                            if (nt == mt) {
                                #pragma unroll
                                for (int i2 = 0; i2 < 4; i2++)
                                    s0[i2] = (g * 4 + i2 <= cl) ? s0[i2] : -1e30f;
                            }
                            sv[nt] = s0;
                        }
                    }
                    // single max reduction (query = cl; reduce regs then g-groups)
                    float mx = -1e30f;
                    #pragma unroll
                    for (int nt = 0; nt < 8; nt++)
                        mx = fmaxf(mx, fmaxf(fmaxf(sv[nt][0], sv[nt][1]),
                                             fmaxf(sv[nt][2], sv[nt][3])));
                    mx = fmaxf(mx, __shfl_xor(mx, 16));
                    mx = fmaxf(mx, __shfl_xor(mx, 32));
                    // exp all entries (invalid ones are -1e30 -> exp = 0), sum
                    float sum = 0.f;
                    #pragma unroll
                    for (int nt = 0; nt < 8; nt++) {
                        #pragma unroll
                        for (int i2 = 0; i2 < 4; i2++) {
                            float p = __expf(sv[nt][i2] - mx);
                            sv[nt][i2] = p;
                            sum += p;
                        }
                    }
                    sum += __shfl_xor(sum, 16);
                    sum += __shfl_xor(sum, 32);
                    float inv = 1.f / sum;
                    // PV: static kt, independent transposes pipeline
                    f4v o = {0.f, 0.f, 0.f, 0.f};
                    #pragma unroll
                    for (int kt = 0; kt < 4; kt++) {
                        if (kt <= (mt >> 1)) {
                            float pe[8];
                            #pragma unroll
                            for (int e = 0; e < 8; e++) {
                                int src = ((g & 1) * 2 + (e >> 2)) * 16 + cl;
                                float a0 = __shfl(sv[2 * kt][e & 3], src);
                                float a1 = __shfl(sv[2 * kt + 1][e & 3], src);
                                pe[e] = (g >> 1) ? a1 : a0;
                            }
                            union { unsigned u[4]; s8v v; } pu;
                            #pragma unroll
                            for (int j = 0; j < 4; j++)
                                pu.u[j] = (unsigned)f2bf(pe[2 * j]) |
                                          ((unsigned)f2bf(pe[2 * j + 1]) << 16);
                            s8v vf = *(const s8v*)(vb + ((headl * 4 + kt) * 4 + g) * 64
                                                   + (cl & 7) * 8);
                            o = mfma16(pu.v, vf, o);
                        }
                    }
                    float invt[4];
                    #pragma unroll
                    for (int i2 = 0; i2 < 4; i2++) invt[i2] = __shfl(inv, g * 4 + i2);
                    unsigned pk0 = (unsigned)f2bf(o[0] * invt[0]) |
                                   ((unsigned)f2bf(o[1] * invt[1]) << 16);
                    unsigned pk1 = (unsigned)f2bf(o[2] * invt[2]) |
                                   ((unsigned)f2bf(o[3] * invt[3]) << 16);
                    if (hf == 0) {                      // per-lane register stash
                        if (ti == 0) { st0a = pk0; st0b = pk1; }
                        else         { st1a = pk0; st1b = pk1; }
                    } else {
                        store_o(xah, mt, 4 + headl, g, cl, pk0, pk1);
                    }
                }
                if (hf == 1) {                          // flush half-0 outputs now
                    int mt0 = (w >> 2), mt1 = (w >> 2) + 4;
                    store_o(xah, mt0, headl, g, cl, st0a, st0b);
                    store_o(xah, mt1, headl, g, cl, st1a, st1b);
                }
            }
            __syncthreads();
        }

        // ---- WO: 32 tiles, 2/wave; unroll 2; D += xs + bo ----
        {
            const unsigned short* pbase = pkw + 36864 + lay * 4096;
            const float* bo = W + OFF_BO + lay * 64;
            #pragma unroll 2
            for (int i = 0; i < 2; i++) {
                int ft = w * 2 + i;
                int mt = ft >> 2, nt = ft & 3;
                const unsigned short* pb = pbase + nt * 1024 + lane * 8;
                f4v acc = {0.f, 0.f, 0.f, 0.f};
                #pragma unroll
                for (int kt = 0; kt < 2; kt++) {
                    s8v ah = *(const s8v*)(xah + ((mt * 2 + kt) * 64 + lane) * 8);
                    s8v bh = *(const s8v*)(pb + kt * 512);
                    s8v bl = *(const s8v*)(pb + PKLO + kt * 512);
                    acc = mfma16(ah, bh, acc);
                    acc = mfma16(ah, bl, acc);
                }
                int row0 = mt * 16 + g * 4, col = nt * 16 + cl;
                float bias = bo[col];
                #pragma unroll
                for (int i2 = 0; i2 < 4; i2++)
                    xs[row0 + i2][col] += acc[i2] + bias;
            }
        }
        __syncthreads();

        ln_frag_hi(xs, xah, W + OFF_LN2G + lay * 64, W + OFF_LN2B + lay * 64, tid);
        __syncthreads();

        // ---- FFN: 4 chunks of 32 rows; hidden bf16-hi in uni ----
        #pragma unroll 1
        for (int ch = 0; ch < 4; ch++) {
            {   // F1: 32 tiles, 2/wave; unroll 2
                const float* b1 = W + OFF_B1 + lay * 256;
                #pragma unroll 2
                for (int i = 0; i < 2; i++) {
                    int ft = w * 2 + i;
                    int mtl = ft >> 4, nt = ft & 15;
                    int mtg = ch * 2 + mtl;
                    const unsigned short* pb = pkw + 49152 + lay * 16384 + nt * 1024 + lane * 8;
                    f4v acc = {0.f, 0.f, 0.f, 0.f};
                    #pragma unroll
                    for (int kt = 0; kt < 2; kt++) {
                        s8v ah = *(const s8v*)(xah + ((mtg * 2 + kt) * 64 + lane) * 8);
                        s8v bh = *(const s8v*)(pb + kt * 512);
                        s8v bl = *(const s8v*)(pb + PKLO + kt * 512);
                        acc = mfma16(ah, bh, acc);
                        acc = mfma16(ah, bl, acc);
                    }
                    int col = nt * 16 + cl;
                    float bias = b1[col];
                    int kt2 = col >> 5, q2 = (col >> 3) & 3, e2 = col & 7;
                    #pragma unroll
                    for (int i2 = 0; i2 < 4; i2++) {
                        int lr = mtl * 16 + g * 4 + i2;
                        float hv = fmaxf(acc[i2] + bias, 0.f);
                        ha[((mtl * 8 + kt2) * 64 + q2 * 16 + (lr & 15)) * 8 + e2] = f2bf(hv);
                    }
                }
            }
            __syncthreads();
            {   // F2: 8 tiles on waves 0-7; K=256
                if (w < 8) {
                    const float* b2 = W + OFF_B2 + lay * 64;
                    int mtl = w >> 2, nt = w & 3;
                    const unsigned short* pb = pkw + 98304 + lay * 16384 + nt * 4096 + lane * 8;
                    f4v acc = {0.f, 0.f, 0.f, 0.f};
                    #pragma unroll 2
                    for (int kt = 0; kt < 8; kt++) {
                        s8v ah = *(const s8v*)(ha + ((mtl * 8 + kt) * 64 + lane) * 8);
                        s8v bh = *(const s8v*)(pb + kt * 512);
                        s8v bl = *(const s8v*)(pb + PKLO + kt * 512);
                        acc = mfma16(ah, bh, acc);
                        acc = mfma16(ah, bl, acc);
                    }
                    int row0 = ch * 32 + mtl * 16 + g * 4, col = nt * 16 + cl;
                    float bias = b2[col];
                    #pragma unroll
                    for (int i2 = 0; i2 < 4; i2++)
                        xs[row0 + i2][col] += acc[i2] + bias;
                }
            }
            __syncthreads();
        }
    }

    // ---- final LN -> xah (bf16-hi frags) ----
    ln_frag_hi(xs, xah, W + OFF_LNFG, W + OFF_LNFB, tid);
    __syncthreads();

    // ---- logits via MFMA (waves 0-7), softmax + loss in C-layout ----
    if (w < 8) {
        int mt = w;
        const unsigned short* pb = pkw + 147456 + lane * 8;
        f4v acc[4];
        #pragma unroll
        for (int nt = 0; nt < 4; nt++) {
            f4v a = {0.f, 0.f, 0.f, 0.f};
            #pragma unroll
            for (int kt = 0; kt < 2; kt++) {
                s8v ah = *(const s8v*)(xah + ((mt * 2 + kt) * 64 + lane) * 8);
                s8v bh = *(const s8v*)(pb + nt * 1024 + kt * 512);
                s8v bl = *(const s8v*)(pb + PKLO + nt * 1024 + kt * 512);
                a = mfma16(ah, bh, a);
                a = mfma16(ah, bl, a);
            }
            float bias = W[OFF_LMB + nt * 16 + cl];
            #pragma unroll
            for (int i2 = 0; i2 < 4; i2++) a[i2] += bias;
            acc[nt] = a;
        }
        // column 64 (row = mt*16+cl): partial dot over dims g*16..g*16+15
        float l2 = 0.f;
        #pragma unroll
        for (int j = 0; j < 16; j++) {
            int d = g * 16 + j;
            int xi = ((mt * 2 + (d >> 5)) * 64 + ((d >> 3) & 3) * 16 + cl) * 8 + (d & 7);
            l2 += bf2f(xah[xi]) * W[OFF_LMW + d * 65 + 64];
        }
        l2 += __shfl_xor(l2, 16);
        l2 += __shfl_xor(l2, 32);
        l2 += W[OFF_LMB + 64];
        float l2t[4];
        #pragma unroll
        for (int i2 = 0; i2 < 4; i2++) l2t[i2] = __shfl(l2, g * 4 + i2);

        float wacc = 0.f;
        #pragma unroll
        for (int i2 = 0; i2 < 4; i2++) {
            float M = fmaxf(fmaxf(acc[0][i2], acc[1][i2]), fmaxf(acc[2][i2], acc[3][i2]));
            M = fmaxf(M, __shfl_xor(M, 1)); M = fmaxf(M, __shfl_xor(M, 2));
            M = fmaxf(M, __shfl_xor(M, 4)); M = fmaxf(M, __shfl_xor(M, 8));
            M = fmaxf(M, l2t[i2]);
            float ss = __expf(acc[0][i2] - M) + __expf(acc[1][i2] - M)
                     + __expf(acc[2][i2] - M) + __expf(acc[3][i2] - M);
            ss += __shfl_xor(ss, 1); ss += __shfl_xor(ss, 2);
            ss += __shfl_xor(ss, 4); ss += __shfl_xor(ss, 8);
            ss += __expf(l2t[i2] - M);
            float lse = M + logf(ss);
            int r = mt * 16 + g * 4 + i2;
            int row = b * NT + r;
            int tg = i64 ? (int)tgt64[row] : tgt32[row];
            float lt = 0.f;
            #pragma unroll
            for (int nt = 0; nt < 4; nt++)
                if (nt * 16 + cl == tg) lt += acc[nt][i2];
            wacc += lt;
            if (cl == 0) {
                if (tg == 64) wacc += l2t[i2];
                wacc -= lse;
                out[row * NV + 64] = l2t[i2];
            }
            #pragma unroll
            for (int nt = 0; nt < 4; nt++)
                out[row * NV + nt * 16 + cl] = acc[nt][i2];
        }
        wacc += __shfl_xor(wacc, 1);  wacc += __shfl_xor(wacc, 2);
        wacc += __shfl_xor(wacc, 4);  wacc += __shfl_xor(wacc, 8);
        wacc += __shfl_xor(wacc, 16); wacc += __shfl_xor(wacc, 32);
        if (lane == 0) wsum[w] = wacc;
    }
    __syncthreads();
    if (tid == 0) {
        float t = 0.f;
        #pragma unroll
        for (int wv = 0; wv < 8; wv++) t += wsum[wv];
        atomicAdd(loss_acc, t);
    }
    __syncthreads();

    // ---- self-check: block 0 thread 0 recomputes row 0 logits (attn = v0) ----
    if (b == 0 && tid == 0) {
        float x0[ND], xn0[ND], v0[ND], h0[NDF];
        int tok0 = i64 ? (int)idx64[0] : idx32[0];
        for (int c = 0; c < ND; c++)
            x0[c] = W[OFF_TOK + tok0 * ND + c] + W[OFF_POS + c];
        for (int l = 0; l < NL; l++) {
            ln_scalar(x0, xn0, W + OFF_LN1G + l * ND, W + OFF_LN1B + l * ND);
            for (int c = 0; c < ND; c++) {
                float a = 0.f;
                for (int i = 0; i < ND; i++)
                    a += xn0[i] * W[OFF_WV + l * ND * ND + i * ND + c];
                v0[c] = a;
            }
            for (int c = 0; c < ND; c++) {
                float a = W[OFF_BO + l * ND + c];
                for (int i = 0; i < ND; i++)
                    a += v0[i] * W[OFF_WO + l * ND * ND + i * ND + c];
                x0[c] += a;
            }
            ln_scalar(x0, xn0, W + OFF_LN2G + l * ND, W + OFF_LN2B + l * ND);
            for (int j = 0; j < NDF; j++) {
                float a = W[OFF_B1 + l * NDF + j];
                for (int i = 0; i < ND; i++)
                    a += xn0[i] * W[OFF_W1 + l * ND * NDF + i * NDF + j];
                h0[j] = fmaxf(a, 0.f);
            }
            for (int c = 0; c < ND; c++) {
                float a = W[OFF_B2 + l * ND + c];
                for (int j = 0; j < NDF; j++)
                    a += h0[j] * W[OFF_W2 + l * NDF * ND + j * ND + c];
                x0[c] += a;
            }
        }
        ln_scalar(x0, xn0, W + OFF_LNFG, W + OFF_LNFB);
        bool bad = false;
        for (int v = 0; v < NV; v++) {
            float lg = W[OFF_LMB + v];
            for (int i = 0; i < ND; i++)
                lg += xn0[i] * W[OFF_LMW + i * NV + v];
            if (!(fabsf(out[v] - lg) <= 0.1f)) bad = true;   // catches NaN
        }
        if (bad) out[0] = 100.0f;
    }
}

// ======================= VALU fallback kernel (round-1, known good) =======================
__global__ __launch_bounds__(1024, 4) void gpt_fwd_valu(
    const float* __restrict__ W, int usepk,
    const void* __restrict__ idxp, const void* __restrict__ tgtp,
    float* __restrict__ out, float* __restrict__ loss_acc,
    const int* __restrict__ flags)
{
    const int fl = *flags;
    if (usepk && !(fl & 8)) return;                    // main kernel handled it

    __shared__ alignas(16) float xs[NT][68];
    __shared__ alignas(16) float xn[NT][68];
    __shared__ alignas(16) unsigned short qs[NT][72];
    __shared__ alignas(16) unsigned short ks[NT][72];
    __shared__ alignas(16) unsigned short vs[NT][72];
    __shared__ alignas(16) float hch[32][264];
    __shared__ float wsum[16];

    const int tid  = threadIdx.x;
    const int lane = tid & 63;
    const int w    = tid >> 6;
    const int b    = blockIdx.x;
    const bool i64 = !(fl & 4);
    const int*       idx32 = (const int*)idxp;
    const long long* idx64 = (const long long*)idxp;
    const int*       tgt32 = (const int*)tgtp;
    const long long* tgt64 = (const long long*)tgtp;

    for (int e = tid * 4; e < NT * ND; e += 4096) {
        int r = e >> 6, c = e & 63;
        int n = b * NT + r;
        int tok = i64 ? (int)idx64[n] : idx32[n];
        float4 te = *(const float4*)&W[OFF_TOK + tok * ND + c];
        float4 pe = *(const float4*)&W[OFF_POS + r * ND + c];
        float4 xv;
        xv.x = te.x + pe.x; xv.y = te.y + pe.y;
        xv.z = te.z + pe.z; xv.w = te.w + pe.w;
        *(float4*)&xs[r][c] = xv;
    }
    __syncthreads();

    for (int lay = 0; lay < NL; lay++) {
        ln_rm(xs, xn, W + OFF_LN1G + lay * 64, W + OFF_LN1B + lay * 64, tid);
        __syncthreads();
        {
            #pragma unroll 1
            for (int mmat = 0; mmat < 3; mmat++) {
                const float* wm = W + (mmat == 0 ? OFF_WQ : (mmat == 1 ? OFF_WK : OFF_WV))
                                    + lay * ND * ND;
                unsigned short (*dstp)[72] = (mmat == 0) ? qs : ((mmat == 1) ? ks : vs);
                float acc[8];
                #pragma unroll
                for (int rr = 0; rr < 8; rr++) acc[rr] = 0.f;
                #pragma unroll 1
                for (int ih = 0; ih < 4; ih++) {
                    float wr[16];
                    #pragma unroll
                    for (int i = 0; i < 16; i++) wr[i] = wm[(ih * 16 + i) * ND + lane];
                    #pragma unroll
                    for (int rr = 0; rr < 8; rr++)
                        fma16(&xn[w * 8 + rr][ih * 16], wr, acc[rr]);
                }
                #pragma unroll
                for (int rr = 0; rr < 8; rr++)
                    dstp[w * 8 + rr][lane] = f2bf(acc[rr]);
            }
        }
        __syncthreads();
        {
            const int head = w & 7, hh = w >> 3;
            const int h8 = head * 8;
            const int r  = lane + hh * 64;
            const float scale = 0.35355339059327373f;
            float qv[8];
            uint4 qq = *(const uint4*)&qs[r][h8];
            unpack8(qq, qv);
            #pragma unroll
            for (int d = 0; d < 8; d++) qv[d] *= scale;
            float m = -1e30f, lsum = 0.f;
            float o[8] = {0, 0, 0, 0, 0, 0, 0, 0};
            for (int base = 0; base <= r; base += 8) {
                float sc[8];
                #pragma unroll
                for (int t = 0; t < 8; t++) {
                    int kk = base + t; kk = kk > 127 ? 127 : kk;
                    uint4 kr = *(const uint4*)&ks[kk][h8];
                    float kf[8]; unpack8(kr, kf);
                    float s = 0.f;
                    #pragma unroll
                    for (int d = 0; d < 8; d++) s = fmaf(qv[d], kf[d], s);
                    sc[t] = (base + t <= r) ? s : -1e30f;
                }
                float cm = fmaxf(fmaxf(fmaxf(sc[0], sc[1]), fmaxf(sc[2], sc[3])),
                                 fmaxf(fmaxf(sc[4], sc[5]), fmaxf(sc[6], sc[7])));
                float nm  = fmaxf(m, cm);
                float fac = __expf(m - nm);
                lsum *= fac;
                #pragma unroll
                for (int d = 0; d < 8; d++) o[d] *= fac;
                #pragma unroll
                for (int t = 0; t < 8; t++) {
                    float p = __expf(sc[t] - nm);
                    int kk = base + t; kk = kk > 127 ? 127 : kk;
                    uint4 vr = *(const uint4*)&vs[kk][h8];
                    float vf[8]; unpack8(vr, vf);
                    lsum += p;
                    #pragma unroll
                    for (int d = 0; d < 8; d++) o[d] = fmaf(p, vf[d], o[d]);
                }
                m = nm;
            }
            float inv = 1.f / lsum;
            #pragma unroll
            for (int d = 0; d < 8; d++) xn[r][h8 + d] = o[d] * inv;
        }
        __syncthreads();
        {
            const float* wo = W + OFF_WO + lay * ND * ND;
            float acc[8];
            #pragma unroll
            for (int rr = 0; rr < 8; rr++) acc[rr] = W[OFF_BO + lay * ND + lane];
            #pragma unroll 1
            for (int ih = 0; ih < 4; ih++) {
                float wr[16];
                #pragma unroll
                for (int i = 0; i < 16; i++) wr[i] = wo[(ih * 16 + i) * ND + lane];
                #pragma unroll
                for (int rr = 0; rr < 8; rr++)
                    fma16(&xn[w * 8 + rr][ih * 16], wr, acc[rr]);
            }
            #pragma unroll
            for (int rr = 0; rr < 8; rr++)
                xs[w * 8 + rr][lane] += acc[rr];
        }
        __syncthreads();
        ln_rm(xs, xn, W + OFF_LN2G + lay * 64, W + OFF_LN2B + lay * 64, tid);
        __syncthreads();
        {
            const float* w1 = W + OFF_W1 + lay * ND * NDF;
            const float* w2 = W + OFF_W2 + lay * NDF * ND;
            const float* b1 = W + OFF_B1 + lay * NDF;
            const float* b2 = W + OFF_B2 + lay * ND;
            for (int ch = 0; ch < 4; ch++) {
                int rbase = ch * 32;
                {
                    int lr = tid >> 5;
                    int j0 = (tid & 31) * 8;
                    int r  = rbase + lr;
                    float4 ba  = *(const float4*)(b1 + j0);
                    float4 bb4 = *(const float4*)(b1 + j0 + 4);
                    float a0 = ba.x,  a1 = ba.y,  a2 = ba.z,  a3 = ba.w;
                    float a4 = bb4.x, a5 = bb4.y, a6 = bb4.z, a7 = bb4.w;
                    #pragma unroll 4
                    for (int i4 = 0; i4 < ND; i4 += 4) {
                        float4 xv = *(const float4*)&xn[r][i4];
                        #pragma unroll
                        for (int s = 0; s < 4; s++) {
                            float xvs = (s == 0) ? xv.x : (s == 1) ? xv.y
                                      : (s == 2) ? xv.z : xv.w;
                            float4 wa = *(const float4*)(w1 + (i4 + s) * NDF + j0);
                            float4 wb = *(const float4*)(w1 + (i4 + s) * NDF + j0 + 4);
                            a0 = fmaf(xvs, wa.x, a0); a1 = fmaf(xvs, wa.y, a1);
                            a2 = fmaf(xvs, wa.z, a2); a3 = fmaf(xvs, wa.w, a3);
                            a4 = fmaf(xvs, wb.x, a4); a5 = fmaf(xvs, wb.y, a5);
                            a6 = fmaf(xvs, wb.z, a6); a7 = fmaf(xvs, wb.w, a7);
                        }
                    }
                    float4 h0v, h1v;
                    h0v.x = fmaxf(a0, 0.f); h0v.y = fmaxf(a1, 0.f);
                    h0v.z = fmaxf(a2, 0.f); h0v.w = fmaxf(a3, 0.f);
                    h1v.x = fmaxf(a4, 0.f); h1v.y = fmaxf(a5, 0.f);
                    h1v.z = fmaxf(a6, 0.f); h1v.w = fmaxf(a7, 0.f);
                    *(float4*)&hch[lr][j0]     = h0v;
                    *(float4*)&hch[lr][j0 + 4] = h1v;
                }
                __syncthreads();
                {
                    int lr = tid >> 5;
                    int i0 = (tid & 31) * 2;
                    int r  = rbase + lr;
                    float a0 = 0.f, a1 = 0.f;
                    #pragma unroll 4
                    for (int j4 = 0; j4 < NDF; j4 += 4) {
                        float4 hv = *(const float4*)&hch[lr][j4];
                        #pragma unroll
                        for (int s = 0; s < 4; s++) {
                            float hvs = (s == 0) ? hv.x : (s == 1) ? hv.y
                                      : (s == 2) ? hv.z : hv.w;
                            float2 w2v = *(const float2*)(w2 + (j4 + s) * ND + i0);
                            a0 = fmaf(hvs, w2v.x, a0); a1 = fmaf(hvs, w2v.y, a1);
                        }
                    }
                    float2 bb2 = *(const float2*)(b2 + i0);
                    xs[r][i0]     += a0 + bb2.x;
                    xs[r][i0 + 1] += a1 + bb2.y;
                }
                __syncthreads();
            }
        }
    }
    ln_rm(xs, xn, W + OFF_LNFG, W + OFF_LNFB, tid);
    __syncthreads();

    {
        const float* lmw = W + OFF_LMW;
        float wacc = 0.f;
        for (int rr = 0; rr < 8; rr++) {
            int r = w * 8 + rr;
            float lg  = W[OFF_LMB + lane];
            float lg2 = W[OFF_LMB + 64];
            #pragma unroll 8
            for (int i = 0; i < ND; i++) {
                float xv = xn[r][i];
                lg  = fmaf(xv, lmw[i * NV + lane], lg);
                lg2 = fmaf(xv, lmw[i * NV + 64],  lg2);
            }
            float M = lg;
            #pragma unroll
            for (int off = 32; off; off >>= 1) M = fmaxf(M, __shfl_xor(M, off));
            M = fmaxf(M, lg2);
            float ssum = __expf(lg - M);
            #pragma unroll
            for (int off = 32; off; off >>= 1) ssum += __shfl_xor(ssum, off);
            ssum += __expf(lg2 - M);
            float lse = M + logf(ssum);
            int row = b * NT + r;
            int tg  = i64 ? (int)tgt64[row] : tgt32[row];
            float lt = (tg < 64) ? __shfl(lg, tg) : lg2;
            wacc += lt - lse;
            out[row * NV + lane] = lg;
            if (lane == 0) out[row * NV + 64] = lg2;
        }
        if (lane == 0) wsum[w] = wacc;
        __syncthreads();
        if (tid == 0) {
            float t = 0.f;
            #pragma unroll
            for (int wv = 0; wv < 16; wv++) t += wsum[wv];
            atomicAdd(loss_acc, t);
        }
    }
}

__global__ void finalize_loss(const float* __restrict__ acc,
                              float* __restrict__ out) {
    out[NBT * NV] = -acc[0] * (1.f / (float)NBT);
}

extern "C" void kernel_launch(void* const* d_in, const int* in_sizes, int n_in,
                              void* d_out, int out_size, void* d_ws, size_t ws_size,
                              hipStream_t stream)
{
    static const int want[21] = {4160, 8192, 192, 192, 12288, 12288, 12288,
                                 12288, 192, 192, 192, 49152, 768, 49152, 192,
                                 64, 64, 4160, 65, 524288, 524288};
    int diag = 0;
    if (n_in != 21) diag = 3;
    else for (int i = 0; i < 21; i++) if (in_sizes[i] != want[i]) { diag = 3; break; }
    if (!diag && out_size != NBT * NV + 1) diag = 4;
    if (!diag && ws_size < (size_t)(OFF_FLAG + 1) * 4) diag = 5;
    if (diag) {
        diag_fill<<<(out_size + 255) / 256, 256, 0, stream>>>(
            (float*)d_out, out_size, (float)diag);
        return;
    }

    float* W = (float*)d_ws;
    float* loss_acc = W + OFF_LOSS;
    int*   flags    = (int*)(W + OFF_FLAG);
    hipMemsetAsync(W + OFF_LOSS, 0, 2 * sizeof(float), stream);

    detect_float<<<1, 256, 0, stream>>>((const unsigned short*)d_in[0], flags);
    detect_int  <<<1, 256, 0, stream>>>((const int*)d_in[19], flags);
    mfma_probe  <<<1, 64,  0, stream>>>(flags);

    CvtArgs a;
    for (int i = 0; i < 19; i++) a.p[i] = d_in[i];
    cvt_params<<<(CVT_TOTAL + 255) / 256, 256, 0, stream>>>(a, W, flags);

    int usepk = (ws_size >= NEED_WS) ? 1 : 0;
    unsigned short* pkw = (unsigned short*)(W + PKF);
    if (usepk)
        pack_weights<<<(PK_ELEMS + 255) / 256, 256, 0, stream>>>(W, pkw);

    gpt_fwd<<<NB, 1024, 0, stream>>>(W, pkw, usepk, d_in[19], d_in[20],
                                     (float*)d_out, loss_acc, flags);
    gpt_fwd_valu<<<NB, 1024, 0, stream>>>(W, usepk, d_in[19], d_in[20],
                                          (float*)d_out, loss_acc, flags);
    finalize_loss<<<1, 1, 0, stream>>>(loss_acc, (float*)d_out);
}

// Round 10
// 2472.698 us; speedup vs baseline: 1.0954x; 1.0310x over previous
//
#include <hip/hip_runtime.h>
#include <hip/hip_bf16.h>

#define NB  4096
#define NT  128
#define ND  64
#define NV  65
#define NL  3
#define NH  8
#define NDF 256
#define NBT (NB*NT)

// fp32 param offsets inside d_ws (element counts)
#define OFF_TOK   0
#define OFF_POS   4160
#define OFF_LN1G  12352
#define OFF_LN1B  12544
#define OFF_WQ    12736
#define OFF_WK    25024
#define OFF_WV    37312
#define OFF_WO    49600
#define OFF_BO    61888
#define OFF_LN2G  62080
#define OFF_LN2B  62272
#define OFF_W1    62464
#define OFF_B1    111616
#define OFF_W2    112384
#define OFF_B2    161536
#define OFF_LNFG  161728
#define OFF_LNFB  161792
#define OFF_LMW   161856
#define OFF_LMB   166016
#define CVT_TOTAL 166081
#define OFF_LOSS  166144   // fp32 loss accumulator slot
#define OFF_FLAG  166145   // flags: bit0 fp32 floats; bit2 int32 ints; bit3 MFMA-layout-BAD

// packed bf16 weights (hi + lo) appended after flag
#define PKF       166148            // float offset of packed region
#define PK_ELEMS  151552            // bf16 elements (hi); lo mirrors at +PK_ELEMS
#define PKLO      151552
#define NEED_WS   ((size_t)(PKF + PK_ELEMS) * 4)

typedef short s8v  __attribute__((ext_vector_type(8)));
typedef float f4v  __attribute__((ext_vector_type(4)));

struct CvtArgs { const void* p[19]; };

__device__ __forceinline__ unsigned short f2bf(float x) {
    unsigned int u = __float_as_uint(x);
    u = (u + 0x7fffu + ((u >> 16) & 1u)) >> 16;   // RNE
    return (unsigned short)u;
}
__device__ __forceinline__ float bf2f(unsigned short h) {
    return __uint_as_float(((unsigned int)h) << 16);
}
__device__ __forceinline__ f4v mfma16(s8v a, s8v b, f4v c) {
    return __builtin_amdgcn_mfma_f32_16x16x32_bf16(a, b, c, 0, 0, 0);
}

__global__ void diag_fill(float* __restrict__ out, int n, float val) {
    int i = blockIdx.x * 256 + threadIdx.x;
    if (i < n) out[i] = val;
}

__global__ void detect_float(const unsigned short* __restrict__ tok,
                             int* __restrict__ flags) {
    int bad = 0;
    for (int i = threadIdx.x; i < 4096; i += 256) {
        float v = __uint_as_float(((unsigned int)tok[i]) << 16);
        if (!(fabsf(v) < 1000.f)) bad = 1;
    }
    if (bad) atomicOr(flags, 1);
}

__global__ void detect_int(const int* __restrict__ idx32,
                           int* __restrict__ flags) {
    int proven = 0;
    #pragma unroll
    for (int j = 0; j < 8; j++) {
        int slot = 2 * (threadIdx.x * 8 + j) + 1;
        if (idx32[slot] != 0) proven = 1;
    }
    if (proven) atomicOr(flags, 4);
}

// param conversion (bf16 or fp32 -> fp32) into workspace
__global__ void cvt_params(CvtArgs a, float* __restrict__ W,
                           const int* __restrict__ flags) {
    int tid = blockIdx.x * 256 + threadIdx.x;
    if (tid >= CVT_TOTAL) return;
    const int offs[20] = {0,4160,12352,12544,12736,25024,37312,49600,61888,
                          62080,62272,62464,111616,112384,161536,161728,
                          161792,161856,166016,166081};
    int s = 0;
    #pragma unroll
    for (int k = 1; k < 19; k++) s += (tid >= offs[k]);
    int local = tid - offs[s];
    if (*flags & 1) {
        W[tid] = ((const float*)a.p[s])[local];
    } else {
        unsigned int v = ((const unsigned short*)a.p[s])[local];
        W[tid] = __uint_as_float(v << 16);
    }
}

// Pack matmul weights into MFMA b-frag order, hi+lo bf16.
// B-frag: lane l elem e holds B[kt*32 + (l>>4)*8 + e][nt*16 + (l&15)]
__global__ void pack_weights(const float* __restrict__ W,
                             unsigned short* __restrict__ pkw) {
    int p = blockIdx.x * 256 + threadIdx.x;
    if (p >= PK_ELEMS) return;
    int srcoff, K, N, perlay, local, ktbits;
    if (p < 49152) {
        int grp = p / 12288; local = p % 12288;
        srcoff = (grp == 0) ? OFF_WQ : (grp == 1) ? OFF_WK
               : (grp == 2) ? OFF_WV : OFF_WO;
        K = 64; N = 64; perlay = 4096; ktbits = 1;
    } else if (p < 98304) {
        local = p - 49152; srcoff = OFF_W1; K = 64; N = 256;
        perlay = 16384; ktbits = 1;
    } else if (p < 147456) {
        local = p - 98304; srcoff = OFF_W2; K = 256; N = 64;
        perlay = 16384; ktbits = 3;
    } else {
        local = p - 147456; srcoff = OFF_LMW; K = 64; N = 65;   // lm head, cols 0..63
        perlay = 4096; ktbits = 1;
    }
    int lay = local / perlay, rem = local % perlay;
    int t = rem >> 9, le = rem & 511, l = le >> 3, e = le & 7;
    int kt = t & ((1 << ktbits) - 1), nt = t >> ktbits;
    int row = kt * 32 + (l >> 4) * 8 + e;
    int col = nt * 16 + (l & 15);
    float v = W[srcoff + lay * K * N + row * N + col];
    unsigned short hi = f2bf(v);
    pkw[p] = hi;
    pkw[PKLO + p] = f2bf(v - bf2f(hi));
}

// Verify A/B operand layout vs HW-verified C/D layout (asymmetric ints).
__global__ void mfma_probe(int* __restrict__ flags) {
    int l = threadIdx.x;
    s8v av, bv;
    int i = l & 15;
    #pragma unroll
    for (int e = 0; e < 8; e++) {
        int k = (l >> 4) * 8 + e;
        av[e] = (short)f2bf((float)(((i * 5 + k * 3) & 7) - 3));
        bv[e] = (short)f2bf((float)(((k * 7 + i * 11) & 7) - 4));
    }
    f4v c = {0.f, 0.f, 0.f, 0.f};
    c = mfma16(av, bv, c);
    int bad = 0;
    #pragma unroll
    for (int reg = 0; reg < 4; reg++) {
        int row = (l >> 4) * 4 + reg, col = l & 15;
        float exp = 0.f;
        for (int k = 0; k < 32; k++)
            exp += (float)(((row * 5 + k * 3) & 7) - 3) *
                   (float)(((k * 7 + col * 11) & 7) - 4);
        if (c[reg] != exp) bad = 1;
    }
    if (bad) atomicOr(flags, 8);
}

__device__ __forceinline__ void unpack8(uint4 u, float* f) {
    f[0] = __uint_as_float(u.x << 16); f[1] = __uint_as_float(u.x & 0xffff0000u);
    f[2] = __uint_as_float(u.y << 16); f[3] = __uint_as_float(u.y & 0xffff0000u);
    f[4] = __uint_as_float(u.z << 16); f[5] = __uint_as_float(u.z & 0xffff0000u);
    f[6] = __uint_as_float(u.w << 16); f[7] = __uint_as_float(u.w & 0xffff0000u);
}

// LayerNorm over D=64, 8 threads/row, fp32 row-major out (VALU path helper)
__device__ __forceinline__ void ln_rm(const float (*src)[68], float (*dst)[68],
                                      const float* __restrict__ g,
                                      const float* __restrict__ bb, int tid) {
    int r = tid >> 3, q = tid & 7;
    int c0 = q * 8;
    float s = 0.f, s2 = 0.f;
    #pragma unroll
    for (int c = 0; c < 8; c++) { float v = src[r][c0 + c]; s += v; s2 += v * v; }
    s += __shfl_xor(s, 1);  s2 += __shfl_xor(s2, 1);
    s += __shfl_xor(s, 2);  s2 += __shfl_xor(s2, 2);
    s += __shfl_xor(s, 4);  s2 += __shfl_xor(s2, 4);
    float mu   = s  * (1.f / 64.f);
    float var  = s2 * (1.f / 64.f) - mu * mu;
    float rstd = rsqrtf(var + 1e-5f);
    #pragma unroll
    for (int c = 0; c < 8; c++) {
        int cc = c0 + c;
        dst[r][cc] = (src[r][cc] - mu) * rstd * g[cc] + bb[cc];
    }
}

// LayerNorm writing bf16-hi a-frag layout: elem (r,col) at
// (((r>>4)*2 + (col>>5))*64 + ((col>>3)&3)*16 + (r&15))*8 + (col&7)
__device__ __forceinline__ void ln_frag_hi(const float (*src)[68],
        unsigned short* __restrict__ dhi,
        const float* __restrict__ g, const float* __restrict__ bb, int tid) {
    int r = tid >> 3, q = tid & 7, c0 = q * 8;
    float s = 0.f, s2 = 0.f;
    #pragma unroll
    for (int c = 0; c < 8; c++) { float v = src[r][c0 + c]; s += v; s2 += v * v; }
    s += __shfl_xor(s, 1);  s2 += __shfl_xor(s2, 1);
    s += __shfl_xor(s, 2);  s2 += __shfl_xor(s2, 2);
    s += __shfl_xor(s, 4);  s2 += __shfl_xor(s2, 4);
    float mu   = s  * (1.f / 64.f);
    float var  = s2 * (1.f / 64.f) - mu * mu;
    float rstd = rsqrtf(var + 1e-5f);
    unsigned uh[4];
    #pragma unroll
    for (int c2 = 0; c2 < 4; c2++) {
        float y0 = (src[r][c0 + c2*2    ] - mu) * rstd * g[c0 + c2*2    ] + bb[c0 + c2*2    ];
        float y1 = (src[r][c0 + c2*2 + 1] - mu) * rstd * g[c0 + c2*2 + 1] + bb[c0 + c2*2 + 1];
        uh[c2] = (unsigned)f2bf(y0) | ((unsigned)f2bf(y1) << 16);
    }
    int di = (((r >> 4) * 2 + (q >> 2)) * 64 + (q & 3) * 16 + (r & 15)) * 8;
    *(uint4*)(dhi + di) = make_uint4(uh[0], uh[1], uh[2], uh[3]);
}

// 16 FMAs of one activation row segment against cached weights (VALU path)
__device__ __forceinline__ void fma16(const float* xr, const float* wr, float& a) {
    float4 x0 = *(const float4*)(xr);
    float4 x1 = *(const float4*)(xr + 4);
    float4 x2 = *(const float4*)(xr + 8);
    float4 x3 = *(const float4*)(xr + 12);
    a = fmaf(x0.x, wr[0],  a); a = fmaf(x0.y, wr[1],  a);
    a = fmaf(x0.z, wr[2],  a); a = fmaf(x0.w, wr[3],  a);
    a = fmaf(x1.x, wr[4],  a); a = fmaf(x1.y, wr[5],  a);
    a = fmaf(x1.z, wr[6],  a); a = fmaf(x1.w, wr[7],  a);
    a = fmaf(x2.x, wr[8],  a); a = fmaf(x2.y, wr[9],  a);
    a = fmaf(x2.z, wr[10], a); a = fmaf(x2.w, wr[11], a);
    a = fmaf(x3.x, wr[12], a); a = fmaf(x3.y, wr[13], a);
    a = fmaf(x3.z, wr[14], a); a = fmaf(x3.w, wr[15], a);
}

// scalar LN for the self-check path
__device__ void ln_scalar(const float* x, float* o,
                          const float* g, const float* bb) {
    float mu = 0.f;
    for (int i = 0; i < ND; i++) mu += x[i];
    mu *= (1.f / 64.f);
    float var = 0.f;
    for (int i = 0; i < ND; i++) { float d = x[i] - mu; var += d * d; }
    var *= (1.f / 64.f);
    float rstd = rsqrtf(var + 1e-5f);
    for (int i = 0; i < ND; i++) o[i] = (x[i] - mu) * rstd * g[i] + bb[i];
}

// write one attention-output quad (packed bf16 pairs) into xah a-frag layout
__device__ __forceinline__ void store_o(unsigned short* xah, int mt, int head,
                                        int g, int cl, unsigned pk0, unsigned pk1) {
    if (cl < 8) {
        unsigned pk[2] = {pk0, pk1};
        #pragma unroll
        for (int i2 = 0; i2 < 4; i2++) {
            int r = mt * 16 + g * 4 + i2;
            int col = head * 8 + cl;
            unsigned v = pk[i2 >> 1];
            unsigned short hv = (unsigned short)((i2 & 1) ? (v >> 16) : (v & 0xffffu));
            int di = (((r >> 4) * 2 + (col >> 5)) * 64 + ((col >> 3) & 3) * 16
                      + (r & 15)) * 8 + (col & 7);
            xah[di] = hv;
        }
    }
}

// ======================= main MFMA kernel: fused full-width phases ===========
// R3-R9 plateau diagnosis: ~50 barrier phases x serial latency tails dominate.
// Fix: stage ALL 8 heads of q/k/vb (48KB) and the FULL 128x256 hidden (64KB)
// in LDS -> 7 barriers/layer instead of 15, 2x tiles/wave/phase, no ostash
// (attention writes xah directly - LN data dead after QKV), F2 uses all 16
// waves. Attention inner loop identical to R5 (proven, no spill). LDS 116.8KB.
__global__ __launch_bounds__(1024, 4) void gpt_fwd(
    const float* __restrict__ W, const unsigned short* __restrict__ pkw,
    int usepk, const void* __restrict__ idxp, const void* __restrict__ tgtp,
    float* __restrict__ out, float* __restrict__ loss_acc,
    const int* __restrict__ flags)
{
    __shared__ alignas(16) float xs[NT][68];            // residual, 34816B
    __shared__ alignas(16) unsigned short xah[8192];    // A-frag hi, 16384B
    __shared__ alignas(16) unsigned short uni[32768];   // q/k/vb (48KB) OR hidden (64KB)
    __shared__ alignas(16) unsigned short zblk[8];      // 16B zeros
    __shared__ float wsum[8];

    unsigned short* q_l = uni;                          // [8][128][8]
    unsigned short* k_l = uni + 8192;                   // [8][128][8]
    unsigned short* vb  = uni + 16384;                  // [8][4kt][4g][8c][8e]
    unsigned short* ha  = uni;                          // hidden [8mt][8kt][64][8]

    const int tid  = threadIdx.x;
    const int lane = tid & 63;
    const int w    = tid >> 6;
    const int cl   = lane & 15;
    const int g    = lane >> 4;
    const int b    = blockIdx.x;
    const int fl   = *flags;
    if (!usepk || (fl & 8)) return;                     // fallback kernel will run
    const bool i64 = !(fl & 4);
    const int*       idx32 = (const int*)idxp;
    const long long* idx64 = (const long long*)idxp;
    const int*       tgt32 = (const int*)tgtp;
    const long long* tgt64 = (const long long*)tgtp;

    if (tid < 8) zblk[tid] = 0;

    // ---- embed: x = tok_emb[idx] + pos_emb ----
    for (int e = tid * 4; e < NT * ND; e += 4096) {
        int r = e >> 6, c = e & 63;
        int n = b * NT + r;
        int tok = i64 ? (int)idx64[n] : idx32[n];
        float4 te = *(const float4*)&W[OFF_TOK + tok * ND + c];
        float4 pe = *(const float4*)&W[OFF_POS + r * ND + c];
        float4 xv;
        xv.x = te.x + pe.x; xv.y = te.y + pe.y;
        xv.z = te.z + pe.z; xv.w = te.w + pe.w;
        *(float4*)&xs[r][c] = xv;
    }
    __syncthreads();

    for (int lay = 0; lay < NL; lay++) {
        ln_frag_hi(xs, xah, W + OFF_LN1G + lay * 64, W + OFF_LN1B + lay * 64, tid);
        __syncthreads();

        // ---- QKV (all heads): 96 tiles, 6/wave ----
        {
            const unsigned short* pbase = pkw + lay * 4096;
            #pragma unroll 1
            for (int i = 0; i < 6; i++) {
                int ft = w * 6 + i;                 // 0..95
                int mat = ft >> 5;
                int rem = ft & 31;
                int mt  = rem >> 2;
                int ntg = rem & 3;
                const unsigned short* pb = pbase + mat * 12288 + ntg * 1024 + lane * 8;
                f4v acc = {0.f, 0.f, 0.f, 0.f};
                #pragma unroll
                for (int kt = 0; kt < 2; kt++) {
                    s8v ah = *(const s8v*)(xah + ((mt * 2 + kt) * 64 + lane) * 8);
                    s8v bh = *(const s8v*)(pb + kt * 512);
                    s8v bl = *(const s8v*)(pb + PKLO + kt * 512);
                    acc = mfma16(ah, bh, acc);
                    acc = mfma16(ah, bl, acc);
                }
                int row0 = mt * 16 + g * 4;
                int fullcol = ntg * 16 + cl;
                int head = fullcol >> 3;            // 0..7
                int dim  = fullcol & 7;
                if (mat == 0) {
                    #pragma unroll
                    for (int i2 = 0; i2 < 4; i2++)
                        q_l[(head * 128 + row0 + i2) * 8 + dim] =
                            f2bf(acc[i2] * 0.35355339059327373f);
                } else if (mat == 1) {
                    #pragma unroll
                    for (int i2 = 0; i2 < 4; i2++)
                        k_l[(head * 128 + row0 + i2) * 8 + dim] = f2bf(acc[i2]);
                } else {
                    #pragma unroll
                    for (int i2 = 0; i2 < 4; i2++) {
                        int key = row0 + i2;
                        vb[((head * 4 + (key >> 5)) * 4 + ((key >> 3) & 3)) * 64
                           + dim * 8 + (key & 7)] = f2bf(acc[i2]);
                    }
                }
            }
        }
        __syncthreads();

        // ---- attention (all heads): 64 tiles, 4/wave; writes xah directly ----
        {
            #pragma unroll 1
            for (int ti = 0; ti < 4; ti++) {
                int t = w + ti * 16;                // 0..63
                int head = t & 7, mt = t >> 3;
                const unsigned short* qsrc = (lane < 16)
                    ? q_l + (head * 128 + mt * 16 + cl) * 8 : zblk;
                s8v qb = *(const s8v*)qsrc;
                float m = -1e30f, lsum = 0.f;
                f4v o = {0.f, 0.f, 0.f, 0.f};
                const int ktmax = mt >> 1;
                #pragma unroll 1
                for (int kt = 0; kt <= ktmax; kt++) {
                    f4v p0, p1;
                    {
                        const unsigned short* ksrc = (lane < 16)
                            ? k_l + (head * 128 + (kt * 2) * 16 + cl) * 8 : zblk;
                        s8v kb = *(const s8v*)ksrc;
                        f4v s0 = {0.f, 0.f, 0.f, 0.f};
                        s0 = mfma16(kb, qb, s0);
                        if (kt * 2 == mt) {
                            #pragma unroll
                            for (int i2 = 0; i2 < 4; i2++)
                                s0[i2] = (g * 4 + i2 <= cl) ? s0[i2] : -1e30f;
                        }
                        p0 = s0;
                    }
                    if (kt * 2 + 1 <= mt) {
                        const unsigned short* ksrc = (lane < 16)
                            ? k_l + (head * 128 + (kt * 2 + 1) * 16 + cl) * 8 : zblk;
                        s8v kb = *(const s8v*)ksrc;
                        f4v s1 = {0.f, 0.f, 0.f, 0.f};
                        s1 = mfma16(kb, qb, s1);
                        if (kt * 2 + 1 == mt) {
                            #pragma unroll
                            for (int i2 = 0; i2 < 4; i2++)
                                s1[i2] = (g * 4 + i2 <= cl) ? s1[i2] : -1e30f;
                        }
                        p1 = s1;
                    } else {
                        p1 = (f4v){-1e30f, -1e30f, -1e30f, -1e30f};
                    }
                    float bm = fmaxf(fmaxf(fmaxf(p0[0], p0[1]), fmaxf(p0[2], p0[3])),
                                     fmaxf(fmaxf(p1[0], p1[1]), fmaxf(p1[2], p1[3])));
                    bm = fmaxf(bm, __shfl_xor(bm, 16));
                    bm = fmaxf(bm, __shfl_xor(bm, 32));
                    float nm  = fmaxf(m, bm);
                    float fac = __expf(m - nm);
                    float ps = 0.f;
                    #pragma unroll
                    for (int i2 = 0; i2 < 4; i2++) {
                        p0[i2] = __expf(p0[i2] - nm); ps += p0[i2];
                        p1[i2] = __expf(p1[i2] - nm); ps += p1[i2];
                    }
                    ps += __shfl_xor(ps, 16);
                    ps += __shfl_xor(ps, 32);
                    lsum = lsum * fac + ps;
                    #pragma unroll
                    for (int i2 = 0; i2 < 4; i2++)
                        o[i2] *= __shfl(fac, g * 4 + i2);
                    // transpose P (C-layout of S^T) to A-frag via shfl
                    float pe[8];
                    #pragma unroll
                    for (int e = 0; e < 8; e++) {
                        int src = ((g & 1) * 2 + (e >> 2)) * 16 + cl;
                        float a0 = __shfl(p0[e & 3], src);
                        float a1 = __shfl(p1[e & 3], src);
                        pe[e] = (g >> 1) ? a1 : a0;
                    }
                    union { unsigned u[4]; s8v v; } pu;
                    #pragma unroll
                    for (int j = 0; j < 4; j++)
                        pu.u[j] = (unsigned)f2bf(pe[2 * j]) |
                                  ((unsigned)f2bf(pe[2 * j + 1]) << 16);
                    s8v vf = *(const s8v*)(vb + ((head * 4 + kt) * 4 + g) * 64
                                           + (cl & 7) * 8);
                    o = mfma16(pu.v, vf, o);
                    m = nm;
                }
                float inv = 1.f / lsum;
                float invt[4];
                #pragma unroll
                for (int i2 = 0; i2 < 4; i2++) invt[i2] = __shfl(inv, g * 4 + i2);
                unsigned pk0 = (unsigned)f2bf(o[0] * invt[0]) |
                               ((unsigned)f2bf(o[1] * invt[1]) << 16);
                unsigned pk1 = (unsigned)f2bf(o[2] * invt[2]) |
                               ((unsigned)f2bf(o[3] * invt[3]) << 16);
                store_o(xah, mt, head, g, cl, pk0, pk1);   // xah LN data dead now
            }
        }
        __syncthreads();

        // ---- WO: 32 tiles, 2/wave; D += xs + bo ----
        {
            const unsigned short* pbase = pkw + 36864 + lay * 4096;
            const float* bo = W + OFF_BO + lay * 64;
            #pragma unroll 1
            for (int i = 0; i < 2; i++) {
                int ft = w * 2 + i;
                int mt = ft >> 2, nt = ft & 3;
                const unsigned short* pb = pbase + nt * 1024 + lane * 8;
                f4v acc = {0.f, 0.f, 0.f, 0.f};
                #pragma unroll
                for (int kt = 0; kt < 2; kt++) {
                    s8v ah = *(const s8v*)(xah + ((mt * 2 + kt) * 64 + lane) * 8);
                    s8v bh = *(const s8v*)(pb + kt * 512);
                    s8v bl = *(const s8v*)(pb + PKLO + kt * 512);
                    acc = mfma16(ah, bh, acc);
                    acc = mfma16(ah, bl, acc);
                }
                int row0 = mt * 16 + g * 4, col = nt * 16 + cl;
                float bias = bo[col];
                #pragma unroll
                for (int i2 = 0; i2 < 4; i2++)
                    xs[row0 + i2][col] += acc[i2] + bias;
            }
        }
        __syncthreads();

        ln_frag_hi(xs, xah, W + OFF_LN2G + lay * 64, W + OFF_LN2B + lay * 64, tid);
        __syncthreads();

        // ---- F1 (full): 128 tiles, 8/wave; relu -> hidden frags in uni ----
        {
            const float* b1 = W + OFF_B1 + lay * 256;
            #pragma unroll 1
            for (int i = 0; i < 8; i++) {
                int ft = w * 8 + i;                 // 0..127
                int mtg = ft >> 4, nt = ft & 15;
                const unsigned short* pb = pkw + 49152 + lay * 16384 + nt * 1024 + lane * 8;
                f4v acc = {0.f, 0.f, 0.f, 0.f};
                #pragma unroll
                for (int kt = 0; kt < 2; kt++) {
                    s8v ah = *(const s8v*)(xah + ((mtg * 2 + kt) * 64 + lane) * 8);
                    s8v bh = *(const s8v*)(pb + kt * 512);
                    s8v bl = *(const s8v*)(pb + PKLO + kt * 512);
                    acc = mfma16(ah, bh, acc);
                    acc = mfma16(ah, bl, acc);
                }
                int col = nt * 16 + cl;
                float bias = b1[col];
                int kt2 = col >> 5, q2 = (col >> 3) & 3, e2 = col & 7;
                #pragma unroll
                for (int i2 = 0; i2 < 4; i2++) {
                    int lr = g * 4 + i2;            // row within 16-row tile
                    float hv = fmaxf(acc[i2] + bias, 0.f);
                    ha[((mtg * 8 + kt2) * 64 + q2 * 16 + lr) * 8 + e2] = f2bf(hv);
                }
            }
        }
        __syncthreads();

        // ---- F2 (full): 32 tiles, 2/wave (ALL 16 waves); K=256 ----
        {
            const float* b2 = W + OFF_B2 + lay * 64;
            #pragma unroll 1
            for (int i = 0; i < 2; i++) {
                int ft = w * 2 + i;                 // 0..31
                int mtl = ft >> 2, nt = ft & 3;
                const unsigned short* pb = pkw + 98304 + lay * 16384 + nt * 4096 + lane * 8;
                f4v acc = {0.f, 0.f, 0.f, 0.f};
                #pragma unroll 2
                for (int kt = 0; kt < 8; kt++) {
                    s8v ah = *(const s8v*)(ha + ((mtl * 8 + kt) * 64 + lane) * 8);
                    s8v bh = *(const s8v*)(pb + kt * 512);
                    s8v bl = *(const s8v*)(pb + PKLO + kt * 512);
                    acc = mfma16(ah, bh, acc);
                    acc = mfma16(ah, bl, acc);
                }
                int row0 = mtl * 16 + g * 4, col = nt * 16 + cl;
                float bias = b2[col];
                #pragma unroll
                for (int i2 = 0; i2 < 4; i2++)
                    xs[row0 + i2][col] += acc[i2] + bias;
            }
        }
        __syncthreads();
    }

    // ---- final LN -> xah (bf16-hi frags) ----
    ln_frag_hi(xs, xah, W + OFF_LNFG, W + OFF_LNFB, tid);
    __syncthreads();

    // ---- logits via MFMA (waves 0-7), softmax + loss in C-layout ----
    if (w < 8) {
        int mt = w;
        const unsigned short* pb = pkw + 147456 + lane * 8;
        f4v acc[4];
        #pragma unroll
        for (int nt = 0; nt < 4; nt++) {
            f4v a = {0.f, 0.f, 0.f, 0.f};
            #pragma unroll
            for (int kt = 0; kt < 2; kt++) {
                s8v ah = *(const s8v*)(xah + ((mt * 2 + kt) * 64 + lane) * 8);
                s8v bh = *(const s8v*)(pb + nt * 1024 + kt * 512);
                s8v bl = *(const s8v*)(pb + PKLO + nt * 1024 + kt * 512);
                a = mfma16(ah, bh, a);
                a = mfma16(ah, bl, a);
            }
            float bias = W[OFF_LMB + nt * 16 + cl];
            #pragma unroll
            for (int i2 = 0; i2 < 4; i2++) a[i2] += bias;
            acc[nt] = a;
        }
        // column 64 (row = mt*16+cl): partial dot over dims g*16..g*16+15
        float l2 = 0.f;
        #pragma unroll
        for (int j = 0; j < 16; j++) {
            int d = g * 16 + j;
            int xi = ((mt * 2 + (d >> 5)) * 64 + ((d >> 3) & 3) * 16 + cl) * 8 + (d & 7);
            l2 += bf2f(xah[xi]) * W[OFF_LMW + d * 65 + 64];
        }
        l2 += __shfl_xor(l2, 16);
        l2 += __shfl_xor(l2, 32);
        l2 += W[OFF_LMB + 64];
        float l2t[4];
        #pragma unroll
        for (int i2 = 0; i2 < 4; i2++) l2t[i2] = __shfl(l2, g * 4 + i2);

        float wacc = 0.f;
        #pragma unroll
        for (int i2 = 0; i2 < 4; i2++) {
            float M = fmaxf(fmaxf(acc[0][i2], acc[1][i2]), fmaxf(acc[2][i2], acc[3][i2]));
            M = fmaxf(M, __shfl_xor(M, 1)); M = fmaxf(M, __shfl_xor(M, 2));
            M = fmaxf(M, __shfl_xor(M, 4)); M = fmaxf(M, __shfl_xor(M, 8));
            M = fmaxf(M, l2t[i2]);
            float ss = __expf(acc[0][i2] - M) + __expf(acc[1][i2] - M)
                     + __expf(acc[2][i2] - M) + __expf(acc[3][i2] - M);
            ss += __shfl_xor(ss, 1); ss += __shfl_xor(ss, 2);
            ss += __shfl_xor(ss, 4); ss += __shfl_xor(ss, 8);
            ss += __expf(l2t[i2] - M);
            float lse = M + logf(ss);
            int r = mt * 16 + g * 4 + i2;
            int row = b * NT + r;
            int tg = i64 ? (int)tgt64[row] : tgt32[row];
            float lt = 0.f;
            #pragma unroll
            for (int nt = 0; nt < 4; nt++)
                if (nt * 16 + cl == tg) lt += acc[nt][i2];
            wacc += lt;
            if (cl == 0) {
                if (tg == 64) wacc += l2t[i2];
                wacc -= lse;
                out[row * NV + 64] = l2t[i2];
            }
            #pragma unroll
            for (int nt = 0; nt < 4; nt++)
                out[row * NV + nt * 16 + cl] = acc[nt][i2];
        }
        wacc += __shfl_xor(wacc, 1);  wacc += __shfl_xor(wacc, 2);
        wacc += __shfl_xor(wacc, 4);  wacc += __shfl_xor(wacc, 8);
        wacc += __shfl_xor(wacc, 16); wacc += __shfl_xor(wacc, 32);
        if (lane == 0) wsum[w] = wacc;
    }
    __syncthreads();
    if (tid == 0) {
        float t = 0.f;
        #pragma unroll
        for (int wv = 0; wv < 8; wv++) t += wsum[wv];
        atomicAdd(loss_acc, t);
    }
    __syncthreads();

    // ---- self-check: block 0 thread 0 recomputes row 0 logits (attn = v0) ----
    if (b == 0 && tid == 0) {
        float x0[ND], xn0[ND], v0[ND], h0[NDF];
        int tok0 = i64 ? (int)idx64[0] : idx32[0];
        for (int c = 0; c < ND; c++)
            x0[c] = W[OFF_TOK + tok0 * ND + c] + W[OFF_POS + c];
        for (int l = 0; l < NL; l++) {
            ln_scalar(x0, xn0, W + OFF_LN1G + l * ND, W + OFF_LN1B + l * ND);
            for (int c = 0; c < ND; c++) {
                float a = 0.f;
                for (int i = 0; i < ND; i++)
                    a += xn0[i] * W[OFF_WV + l * ND * ND + i * ND + c];
                v0[c] = a;
            }
            for (int c = 0; c < ND; c++) {
                float a = W[OFF_BO + l * ND + c];
                for (int i = 0; i < ND; i++)
                    a += v0[i] * W[OFF_WO + l * ND * ND + i * ND + c];
                x0[c] += a;
            }
            ln_scalar(x0, xn0, W + OFF_LN2G + l * ND, W + OFF_LN2B + l * ND);
            for (int j = 0; j < NDF; j++) {
                float a = W[OFF_B1 + l * NDF + j];
                for (int i = 0; i < ND; i++)
                    a += xn0[i] * W[OFF_W1 + l * ND * NDF + i * NDF + j];
                h0[j] = fmaxf(a, 0.f);
            }
            for (int c = 0; c < ND; c++) {
                float a = W[OFF_B2 + l * ND + c];
                for (int j = 0; j < NDF; j++)
                    a += h0[j] * W[OFF_W2 + l * NDF * ND + j * ND + c];
                x0[c] += a;
            }
        }
        ln_scalar(x0, xn0, W + OFF_LNFG, W + OFF_LNFB);
        bool bad = false;
        for (int v = 0; v < NV; v++) {
            float lg = W[OFF_LMB + v];
            for (int i = 0; i < ND; i++)
                lg += xn0[i] * W[OFF_LMW + i * NV + v];
            if (!(fabsf(out[v] - lg) <= 0.1f)) bad = true;   // catches NaN
        }
        if (bad) out[0] = 100.0f;
    }
}

// ======================= VALU fallback kernel (round-1, known good) =======================
__global__ __launch_bounds__(1024, 4) void gpt_fwd_valu(
    const float* __restrict__ W, int usepk,
    const void* __restrict__ idxp, const void* __restrict__ tgtp,
    float* __restrict__ out, float* __restrict__ loss_acc,
    const int* __restrict__ flags)
{
    const int fl = *flags;
    if (usepk && !(fl & 8)) return;                    // main kernel handled it

    __shared__ alignas(16) float xs[NT][68];
    __shared__ alignas(16) float xn[NT][68];
    __shared__ alignas(16) unsigned short qs[NT][72];
    __shared__ alignas(16) unsigned short ks[NT][72];
    __shared__ alignas(16) unsigned short vs[NT][72];
    __shared__ alignas(16) float hch[32][264];
    __shared__ float wsum[16];

    const int tid  = threadIdx.x;
    const int lane = tid & 63;
    const int w    = tid >> 6;
    const int b    = blockIdx.x;
    const bool i64 = !(fl & 4);
    const int*       idx32 = (const int*)idxp;
    const long long* idx64 = (const long long*)idxp;
    const int*       tgt32 = (const int*)tgtp;
    const long long* tgt64 = (const long long*)tgtp;

    for (int e = tid * 4; e < NT * ND; e += 4096) {
        int r = e >> 6, c = e & 63;
        int n = b * NT + r;
        int tok = i64 ? (int)idx64[n] : idx32[n];
        float4 te = *(const float4*)&W[OFF_TOK + tok * ND + c];
        float4 pe = *(const float4*)&W[OFF_POS + r * ND + c];
        float4 xv;
        xv.x = te.x + pe.x; xv.y = te.y + pe.y;
        xv.z = te.z + pe.z; xv.w = te.w + pe.w;
        *(float4*)&xs[r][c] = xv;
    }
    __syncthreads();

    for (int lay = 0; lay < NL; lay++) {
        ln_rm(xs, xn, W + OFF_LN1G + lay * 64, W + OFF_LN1B + lay * 64, tid);
        __syncthreads();
        {
            #pragma unroll 1
            for (int mmat = 0; mmat < 3; mmat++) {
                const float* wm = W + (mmat == 0 ? OFF_WQ : (mmat == 1 ? OFF_WK : OFF_WV))
                                    + lay * ND * ND;
                unsigned short (*dstp)[72] = (mmat == 0) ? qs : ((mmat == 1) ? ks : vs);
                float acc[8];
                #pragma unroll
                for (int rr = 0; rr < 8; rr++) acc[rr] = 0.f;
                #pragma unroll 1
                for (int ih = 0; ih < 4; ih++) {
                    float wr[16];
                    #pragma unroll
                    for (int i = 0; i < 16; i++) wr[i] = wm[(ih * 16 + i) * ND + lane];
                    #pragma unroll
                    for (int rr = 0; rr < 8; rr++)
                        fma16(&xn[w * 8 + rr][ih * 16], wr, acc[rr]);
                }
                #pragma unroll
                for (int rr = 0; rr < 8; rr++)
                    dstp[w * 8 + rr][lane] = f2bf(acc[rr]);
            }
        }
        __syncthreads();
        {
            const int head = w & 7, hh = w >> 3;
            const int h8 = head * 8;
            const int r  = lane + hh * 64;
            const float scale = 0.35355339059327373f;
            float qv[8];
            uint4 qq = *(const uint4*)&qs[r][h8];
            unpack8(qq, qv);
            #pragma unroll
            for (int d = 0; d < 8; d++) qv[d] *= scale;
            float m = -1e30f, lsum = 0.f;
            float o[8] = {0, 0, 0, 0, 0, 0, 0, 0};
            for (int base = 0; base <= r; base += 8) {
                float sc[8];
                #pragma unroll
                for (int t = 0; t < 8; t++) {
                    int kk = base + t; kk = kk > 127 ? 127 : kk;
                    uint4 kr = *(const uint4*)&ks[kk][h8];
                    float kf[8]; unpack8(kr, kf);
                    float s = 0.f;
                    #pragma unroll
                    for (int d = 0; d < 8; d++) s = fmaf(qv[d], kf[d], s);
                    sc[t] = (base + t <= r) ? s : -1e30f;
                }
                float cm = fmaxf(fmaxf(fmaxf(sc[0], sc[1]), fmaxf(sc[2], sc[3])),
                                 fmaxf(fmaxf(sc[4], sc[5]), fmaxf(sc[6], sc[7])));
                float nm  = fmaxf(m, cm);
                float fac = __expf(m - nm);
                lsum *= fac;
                #pragma unroll
                for (int d = 0; d < 8; d++) o[d] *= fac;
                #pragma unroll
                for (int t = 0; t < 8; t++) {
                    float p = __expf(sc[t] - nm);
                    int kk = base + t; kk = kk > 127 ? 127 : kk;
                    uint4 vr = *(const uint4*)&vs[kk][h8];
                    float vf[8]; unpack8(vr, vf);
                    lsum += p;
                    #pragma unroll
                    for (int d = 0; d < 8; d++) o[d] = fmaf(p, vf[d], o[d]);
                }
                m = nm;
            }
            float inv = 1.f / lsum;
            #pragma unroll
            for (int d = 0; d < 8; d++) xn[r][h8 + d] = o[d] * inv;
        }
        __syncthreads();
        {
            const float* wo = W + OFF_WO + lay * ND * ND;
            float acc[8];
            #pragma unroll
            for (int rr = 0; rr < 8; rr++) acc[rr] = W[OFF_BO + lay * ND + lane];
            #pragma unroll 1
            for (int ih = 0; ih < 4; ih++) {
                float wr[16];
                #pragma unroll
                for (int i = 0; i < 16; i++) wr[i] = wo[(ih * 16 + i) * ND + lane];
                #pragma unroll
                for (int rr = 0; rr < 8; rr++)
                    fma16(&xn[w * 8 + rr][ih * 16], wr, acc[rr]);
            }
            #pragma unroll
            for (int rr = 0; rr < 8; rr++)
                xs[w * 8 + rr][lane] += acc[rr];
        }
        __syncthreads();
        ln_rm(xs, xn, W + OFF_LN2G + lay * 64, W + OFF_LN2B + lay * 64, tid);
        __syncthreads();
        {
            const float* w1 = W + OFF_W1 + lay * ND * NDF;
            const float* w2 = W + OFF_W2 + lay * NDF * ND;
            const float* b1 = W + OFF_B1 + lay * NDF;
            const float* b2 = W + OFF_B2 + lay * ND;
            for (int ch = 0; ch < 4; ch++) {
                int rbase = ch * 32;
                {
                    int lr = tid >> 5;
                    int j0 = (tid & 31) * 8;
                    int r  = rbase + lr;
                    float4 ba  = *(const float4*)(b1 + j0);
                    float4 bb4 = *(const float4*)(b1 + j0 + 4);
                    float a0 = ba.x,  a1 = ba.y,  a2 = ba.z,  a3 = ba.w;
                    float a4 = bb4.x, a5 = bb4.y, a6 = bb4.z, a7 = bb4.w;
                    #pragma unroll 4
                    for (int i4 = 0; i4 < ND; i4 += 4) {
                        float4 xv = *(const float4*)&xn[r][i4];
                        #pragma unroll
                        for (int s = 0; s < 4; s++) {
                            float xvs = (s == 0) ? xv.x : (s == 1) ? xv.y
                                      : (s == 2) ? xv.z : xv.w;
                            float4 wa = *(const float4*)(w1 + (i4 + s) * NDF + j0);
                            float4 wb = *(const float4*)(w1 + (i4 + s) * NDF + j0 + 4);
                            a0 = fmaf(xvs, wa.x, a0); a1 = fmaf(xvs, wa.y, a1);
                            a2 = fmaf(xvs, wa.z, a2); a3 = fmaf(xvs, wa.w, a3);
                            a4 = fmaf(xvs, wb.x, a4); a5 = fmaf(xvs, wb.y, a5);
                            a6 = fmaf(xvs, wb.z, a6); a7 = fmaf(xvs, wb.w, a7);
                        }
                    }
                    float4 h0v, h1v;
                    h0v.x = fmaxf(a0, 0.f); h0v.y = fmaxf(a1, 0.f);
                    h0v.z = fmaxf(a2, 0.f); h0v.w = fmaxf(a3, 0.f);
                    h1v.x = fmaxf(a4, 0.f); h1v.y = fmaxf(a5, 0.f);
                    h1v.z = fmaxf(a6, 0.f); h1v.w = fmaxf(a7, 0.f);
                    *(float4*)&hch[lr][j0]     = h0v;
                    *(float4*)&hch[lr][j0 + 4] = h1v;
                }
                __syncthreads();
                {
                    int lr = tid >> 5;
                    int i0 = (tid & 31) * 2;
                    int r  = rbase + lr;
                    float a0 = 0.f, a1 = 0.f;
                    #pragma unroll 4
                    for (int j4 = 0; j4 < NDF; j4 += 4) {
                        float4 hv = *(const float4*)&hch[lr][j4];
                        #pragma unroll
                        for (int s = 0; s < 4; s++) {
                            float hvs = (s == 0) ? hv.x : (s == 1) ? hv.y
                                      : (s == 2) ? hv.z : hv.w;
                            float2 w2v = *(const float2*)(w2 + (j4 + s) * ND + i0);
                            a0 = fmaf(hvs, w2v.x, a0); a1 = fmaf(hvs, w2v.y, a1);
                        }
                    }
                    float2 bb2 = *(const float2*)(b2 + i0);
                    xs[r][i0]     += a0 + bb2.x;
                    xs[r][i0 + 1] += a1 + bb2.y;
                }
                __syncthreads();
            }
        }
    }
    ln_rm(xs, xn, W + OFF_LNFG, W + OFF_LNFB, tid);
    __syncthreads();

    {
        const float* lmw = W + OFF_LMW;
        float wacc = 0.f;
        for (int rr = 0; rr < 8; rr++) {
            int r = w * 8 + rr;
            float lg  = W[OFF_LMB + lane];
            float lg2 = W[OFF_LMB + 64];
            #pragma unroll 8
            for (int i = 0; i < ND; i++) {
                float xv = xn[r][i];
                lg  = fmaf(xv, lmw[i * NV + lane], lg);
                lg2 = fmaf(xv, lmw[i * NV + 64],  lg2);
            }
            float M = lg;
            #pragma unroll
            for (int off = 32; off; off >>= 1) M = fmaxf(M, __shfl_xor(M, off));
            M = fmaxf(M, lg2);
            float ssum = __expf(lg - M);
            #pragma unroll
            for (int off = 32; off; off >>= 1) ssum += __shfl_xor(ssum, off);
            ssum += __expf(lg2 - M);
            float lse = M + logf(ssum);
            int row = b * NT + r;
            int tg  = i64 ? (int)tgt64[row] : tgt32[row];
            float lt = (tg < 64) ? __shfl(lg, tg) : lg2;
            wacc += lt - lse;
            out[row * NV + lane] = lg;
            if (lane == 0) out[row * NV + 64] = lg2;
        }
        if (lane == 0) wsum[w] = wacc;
        __syncthreads();
        if (tid == 0) {
            float t = 0.f;
            #pragma unroll
            for (int wv = 0; wv < 16; wv++) t += wsum[wv];
            atomicAdd(loss_acc, t);
        }
    }
}

__global__ void finalize_loss(const float* __restrict__ acc,
                              float* __restrict__ out) {
    out[NBT * NV] = -acc[0] * (1.f / (float)NBT);
}

extern "C" void kernel_launch(void* const* d_in, const int* in_sizes, int n_in,
                              void* d_out, int out_size, void* d_ws, size_t ws_size,
                              hipStream_t stream)
{
    static const int want[21] = {4160, 8192, 192, 192, 12288, 12288, 12288,
                                 12288, 192, 192, 192, 49152, 768, 49152, 192,
                                 64, 64, 4160, 65, 524288, 524288};
    int diag = 0;
    if (n_in != 21) diag = 3;
    else for (int i = 0; i < 21; i++) if (in_sizes[i] != want[i]) { diag = 3; break; }
    if (!diag && out_size != NBT * NV + 1) diag = 4;
    if (!diag && ws_size < (size_t)(OFF_FLAG + 1) * 4) diag = 5;
    if (diag) {
        diag_fill<<<(out_size + 255) / 256, 256, 0, stream>>>(
            (float*)d_out, out_size, (float)diag);
        return;
    }

    float* W = (float*)d_ws;
    float* loss_acc = W + OFF_LOSS;
    int*   flags    = (int*)(W + OFF_FLAG);
    hipMemsetAsync(W + OFF_LOSS, 0, 2 * sizeof(float), stream);

    detect_float<<<1, 256, 0, stream>>>((const unsigned short*)d_in[0], flags);
    detect_int  <<<1, 256, 0, stream>>>((const int*)d_in[19], flags);
    mfma_probe  <<<1, 64,  0, stream>>>(flags);

    CvtArgs a;
    for (int i = 0; i < 19; i++) a.p[i] = d_in[i];
    cvt_params<<<(CVT_TOTAL + 255) / 256, 256, 0, stream>>>(a, W, flags);

    int usepk = (ws_size >= NEED_WS) ? 1 : 0;
    unsigned short* pkw = (unsigned short*)(W + PKF);
    if (usepk)
        pack_weights<<<(PK_ELEMS + 255) / 256, 256, 0, stream>>>(W, pkw);

    gpt_fwd<<<NB, 1024, 0, stream>>>(W, pkw, usepk, d_in[19], d_in[20],
                                     (float*)d_out, loss_acc, flags);
    gpt_fwd_valu<<<NB, 1024, 0, stream>>>(W, usepk, d_in[19], d_in[20],
                                          (float*)d_out, loss_acc, flags);
    finalize_loss<<<1, 1, 0, stream>>>(loss_acc, (float*)d_out);
}